// Round 2
// 14759.016 us; speedup vs baseline: 1.5802x; 1.5802x over previous
//
#include <hip/hip_runtime.h>
#include <hip/hip_bf16.h>
#include <cstdint>

// MixTransformer: B=2,S=1024,D=2048,H=16,KVH=8,HD=128,DFF=8192,E=8,K=2,R=16
// Round 6: resubmit of Round-5 design (infra failure, no counters) with
// defensive hardening: m0 guard, zero-fill of out-of-range B LDS columns
// (no uninitialized LDS feeding MFMA). Design: 128x128-tile MFMA GEMM
// (reg-staged, issue-early/write-late prefetch, template<FID>), split-K w2,
// batched LoRA t-projections, dedicated t2 reduction.

typedef __hip_bfloat16 bf16;
typedef unsigned short u16;
typedef unsigned int u32;
typedef __attribute__((ext_vector_type(8))) short short8;
typedef __attribute__((ext_vector_type(4))) float floatx4;

#define NT 2048      // B*S
#define DMODEL 2048
#define DFF 8192
#define NH 512       // rows per MoE quarter-batch

__device__ __forceinline__ float ldin(const void* p, size_t i, int isf){
  return isf ? ((const float*)p)[i] : __bfloat162float(((const bf16*)p)[i]);
}
__device__ __forceinline__ u16 f2bu(float v){ bf16 h = __float2bfloat16(v); return *(u16*)&h; }
__device__ __forceinline__ float bu2f(u16 v){ u32 x = ((u32)v) << 16; return __uint_as_float(x); }
__device__ __forceinline__ u32 pk2(u16 a, u16 b){ return (u32)a | ((u32)b << 16); }

// ---------------- dtype detection: cos[0] == 1.0f ----------------
__global__ void detect_k(const void* __restrict__ cosp, int* __restrict__ flag){
  if (threadIdx.x == 0 && blockIdx.x == 0){
    u32 w = *(const u32*)cosp;
    flag[0] = (w == 0x3F800000u) ? 1 : 0;   // 1 = float32 inputs, 0 = bf16
  }
}

// ---------------- RMSNorm producing hi/lo bf16 split ----------------
__global__ __launch_bounds__(256) void rmsnorm_split(const int* __restrict__ flagp,
                                                     const void* __restrict__ x, const void* __restrict__ w,
                                                     bf16* __restrict__ hi, bf16* __restrict__ lo){
  int isf = flagp[0];
  int row = blockIdx.x; int tid = threadIdx.x;
  float ss = 0.f;
  for (int d = tid; d < DMODEL; d += 256){ float v = ldin(x, (size_t)row * DMODEL + d, isf); ss = fmaf(v, v, ss); }
  __shared__ float red[256];
  red[tid] = ss; __syncthreads();
  for (int s = 128; s > 0; s >>= 1){ if (tid < s) red[tid] += red[tid + s]; __syncthreads(); }
  float m = red[0] / (float)DMODEL + 1e-5f;
  float r = rsqrtf(m); r = r * (1.5f - 0.5f * m * r * r);  // Newton refine
  for (int d = tid; d < DMODEL; d += 256){
    float v = ldin(x, (size_t)row * DMODEL + d, isf) * r * ldin(w, d, isf);
    bf16 vh = __float2bfloat16(v);
    hi[(size_t)row * DMODEL + d] = vh;
    lo[(size_t)row * DMODEL + d] = __float2bfloat16(v - __bfloat162float(vh));
  }
}

// ---------------- RMSNorm f32 -> bf16 ----------------
__global__ __launch_bounds__(256) void rmsnorm_f32(const int* __restrict__ flagp,
                                                   const float* __restrict__ x, const void* __restrict__ w,
                                                   bf16* __restrict__ out){
  int isf = flagp[0];
  int row = blockIdx.x; int tid = threadIdx.x;
  const float* xr = x + (size_t)row * DMODEL;
  float ss = 0.f;
  for (int d = tid; d < DMODEL; d += 256){ float v = xr[d]; ss = fmaf(v, v, ss); }
  __shared__ float red[256];
  red[tid] = ss; __syncthreads();
  for (int s = 128; s > 0; s >>= 1){ if (tid < s) red[tid] += red[tid + s]; __syncthreads(); }
  float m = red[0] / (float)DMODEL + 1e-5f;
  float r = rsqrtf(m); r = r * (1.5f - 0.5f * m * r * r);
  for (int d = tid; d < DMODEL; d += 256)
    out[(size_t)row * DMODEL + d] = __float2bfloat16(xr[d] * r * ldin(w, d, isf));
}

// ---------------- Gate logits in f64 (routing precision) ----------------
__global__ __launch_bounds__(256) void logits_k(const int* __restrict__ flagp,
                                                const float* __restrict__ x, const void* __restrict__ w,
                                                const void* __restrict__ gw, float* __restrict__ out){
  int isf = flagp[0];
  int row = blockIdx.x; int tid = threadIdx.x;
  const float* xr = x + (size_t)row * DMODEL;
  __shared__ double red[256];
  double ss = 0.0;
  for (int d = tid; d < DMODEL; d += 256){ double v = xr[d]; ss += v * v; }
  red[tid] = ss; __syncthreads();
  for (int s = 128; s > 0; s >>= 1){ if (tid < s) red[tid] += red[tid + s]; __syncthreads(); }
  double scale = 1.0 / sqrt(red[0] / (double)DMODEL + 1e-5);
  double acc[8] = {0,0,0,0,0,0,0,0};
  for (int d = tid; d < DMODEL; d += 256){
    double sv = (double)xr[d] * scale * (double)ldin(w, d, isf);
    #pragma unroll
    for (int e = 0; e < 8; e++) acc[e] += sv * (double)ldin(gw, (size_t)d * 8 + e, isf);
  }
  __shared__ double red8[256][8];
  #pragma unroll
  for (int e = 0; e < 8; e++) red8[tid][e] = acc[e];
  __syncthreads();
  for (int s = 128; s > 0; s >>= 1){
    if (tid < s){ for (int e = 0; e < 8; e++) red8[tid][e] += red8[tid + s][e]; }
    __syncthreads();
  }
  if (tid < 8) out[row * 8 + tid] = (float)red8[0][tid];
}

// ---------------- Routing -> dense ew[NT][8] (0 for unselected) ----------------
__global__ void route_ew(const float* __restrict__ logits, float* __restrict__ ew){
  int row = blockIdx.x * 256 + threadIdx.x;
  if (row >= NT) return;
  float l[8]; float mx = -1e30f;
  for (int e = 0; e < 8; e++){ l[e] = logits[row * 8 + e]; mx = fmaxf(mx, l[e]); }
  float p[8];
  for (int e = 0; e < 8; e++) p[e] = expf(l[e] - mx);
  int e1 = 0; float b1v = p[0];
  for (int e = 1; e < 8; e++) if (p[e] > b1v){ b1v = p[e]; e1 = e; }
  int e2 = -1; float b2v = -1.f;
  for (int e = 0; e < 8; e++) if (e != e1 && p[e] > b2v){ b2v = p[e]; e2 = e; }
  float s = b1v + b2v;
  for (int e = 0; e < 8; e++){
    float w = 0.f;
    if (e == e1) w = b1v / s;
    else if (e == e2) w = b2v / s;
    ew[row * 8 + e] = w;
  }
}

__global__ void zero_f(float* __restrict__ p, int n){
  int i = blockIdx.x * 256 + threadIdx.x;
  if (i < n) p[i] = 0.f;
}
__global__ void fill_b(bf16* __restrict__ p, float v, int n){
  int i = blockIdx.x * 256 + threadIdx.x;
  if (i < n) p[i] = __float2bfloat16(v);
}

// ---------------- 128x128-tile MFMA GEMM ----------------
// C = A@W (+fidelity passes) (+ 2*lt@lB LoRA epilogue)
// A,A2: bf16 [M][lda] (A2 = lo split when FID). W: f32 or bf16 by flag.
// W element (k,n) at: wOff + k*ldw + (n>>4)*wstride + (n&15)   (wstride=16 -> plain)
// FID: acc += Ahi*Whi + Alo*Whi (+ Ahi*Wlo when W is f32).
// mode 0: Cb=bf16(c); 1: Cf=c; 2: w=ew8[gm*8+eIdx]; if(w) atomicAdd(Cf, c*w)
// Split-K via gridDim.z (mode 2 only); LoRA applied only on z==0 chunk.
// Requires M%128==0, Kd%(32*gridDim.z)==0. N guarded (OOB cols stage zeros).
template<int FID>
__global__ __launch_bounds__(256) void gemm128_t(
    const int* __restrict__ flagp,
    const bf16* __restrict__ A, const bf16* __restrict__ A2, int lda,
    const void* __restrict__ W, long long wOff, int ldw, long long wstride,
    float* __restrict__ Cf, bf16* __restrict__ Cb, int ldc,
    int M, int N, int Kd,
    const float* __restrict__ lt, int ldt,
    const void* __restrict__ lB, long long lbOff, int ldlB,
    const float* __restrict__ ew8, int eIdx, int mode)
{
  int isf = flagp[0];
  int m0 = blockIdx.x * 128;
  int n0 = blockIdx.y * 128;
  if (m0 >= M) return;
  int nz = gridDim.z;
  int ksteps = (Kd >> 5) / nz;
  int k0beg = blockIdx.z * ksteps * 32;

  __shared__ __align__(16) u16 Ah[128][32];                 // 8 KB, linear 64B rows
  __shared__ __align__(16) u16 Bh[128][40];                 // 10 KB, [n][k], pad->aligned b128
  __shared__ __align__(16) u16 Al[FID ? 128 : 1][32];
  __shared__ __align__(16) u16 Bl[FID ? 128 : 1][40];

  int tid = threadIdx.x;
  int wv = tid >> 6, ln = tid & 63;
  int wr = wv >> 1, wc = wv & 1;

  // A staging: rows s_ar, s_ar+64; 8-elem chunk s_ac (coalesced: 4 lanes = 64B row)
  int s_ar = tid >> 2;
  int s_ac = (tid & 3) * 8;
  const bf16* Ap0 = A + (size_t)(m0 + s_ar) * lda + s_ac;
  const bf16* Ap1 = A + (size_t)(m0 + s_ar + 64) * lda + s_ac;
  const bf16* Ap0l = Ap0; const bf16* Ap1l = Ap1;
  if (FID){ Ap0l = A2 + (size_t)(m0 + s_ar) * lda + s_ac; Ap1l = A2 + (size_t)(m0 + s_ar + 64) * lda + s_ac; }

  // B staging: col pair (s_bn, s_bn+1), k-octet s_bk
  int s_bn = (tid & 63) * 2;
  int s_bk = (tid >> 6) * 8;
  int gn0 = n0 + s_bn;
  bool bval = gn0 < N;
  long long colOff0 = wOff + (long long)(gn0 >> 4) * wstride + (gn0 & 15);
  const float* Wf = (const float*)W;
  const bf16*  Wb = (const bf16*)W;

  floatx4 acc[4][4];
  #pragma unroll
  for (int a = 0; a < 4; a++)
    #pragma unroll
    for (int b = 0; b < 4; b++) acc[a][b] = (floatx4){0.f, 0.f, 0.f, 0.f};

  uint4 pa0 = {0,0,0,0}, pa1 = {0,0,0,0}, pl0 = {0,0,0,0}, pl1 = {0,0,0,0};
  float pbf[16];
  u32 pbb[8];
  #pragma unroll
  for (int i = 0; i < 16; i++) pbf[i] = 0.f;
  #pragma unroll
  for (int i = 0; i < 8; i++) pbb[i] = 0;

  // prefetch first K-tile
  pa0 = *(const uint4*)(Ap0 + k0beg);
  pa1 = *(const uint4*)(Ap1 + k0beg);
  if (FID){ pl0 = *(const uint4*)(Ap0l + k0beg); pl1 = *(const uint4*)(Ap1l + k0beg); }
  if (bval){
    if (isf){
      #pragma unroll
      for (int i = 0; i < 8; i++){
        float2 v = *(const float2*)(Wf + ((long long)(k0beg + s_bk + i) * ldw + colOff0));
        pbf[i] = v.x; pbf[8 + i] = v.y;
      }
    } else {
      #pragma unroll
      for (int i = 0; i < 8; i++)
        pbb[i] = *(const u32*)(Wb + ((long long)(k0beg + s_bk + i) * ldw + colOff0));
    }
  }

  for (int ks = 0; ks < ksteps; ks++){
    __syncthreads();    // previous iteration's fragment reads complete
    // ---- commit staged tile to LDS ----
    *(uint4*)&Ah[s_ar][s_ac] = pa0;
    *(uint4*)&Ah[s_ar + 64][s_ac] = pa1;
    if (FID){
      *(uint4*)&Al[s_ar][s_ac] = pl0;
      *(uint4*)&Al[s_ar + 64][s_ac] = pl1;
    }
    {
      u16 h[16], l[16];
      if (bval && isf){
        #pragma unroll
        for (int i = 0; i < 16; i++){ h[i] = f2bu(pbf[i]); l[i] = f2bu(pbf[i] - bu2f(h[i])); }
      } else if (bval){
        #pragma unroll
        for (int i = 0; i < 8; i++){ h[i] = (u16)(pbb[i] & 0xffff); h[8 + i] = (u16)(pbb[i] >> 16); l[i] = 0; l[8 + i] = 0; }
      } else {
        #pragma unroll
        for (int i = 0; i < 16; i++){ h[i] = 0; l[i] = 0; }
      }
      uint4 H0, H1;
      H0.x = pk2(h[0], h[1]);  H0.y = pk2(h[2], h[3]);  H0.z = pk2(h[4], h[5]);  H0.w = pk2(h[6], h[7]);
      H1.x = pk2(h[8], h[9]);  H1.y = pk2(h[10], h[11]); H1.z = pk2(h[12], h[13]); H1.w = pk2(h[14], h[15]);
      *(uint4*)&Bh[s_bn][s_bk]     = H0;
      *(uint4*)&Bh[s_bn + 1][s_bk] = H1;
      if (FID && isf){
        uint4 L0, L1;
        L0.x = pk2(l[0], l[1]);  L0.y = pk2(l[2], l[3]);  L0.z = pk2(l[4], l[5]);  L0.w = pk2(l[6], l[7]);
        L1.x = pk2(l[8], l[9]);  L1.y = pk2(l[10], l[11]); L1.z = pk2(l[12], l[13]); L1.w = pk2(l[14], l[15]);
        *(uint4*)&Bl[s_bn][s_bk]     = L0;
        *(uint4*)&Bl[s_bn + 1][s_bk] = L1;
      }
    }
    // ---- issue next K-tile loads (latency hides under MFMA phase) ----
    if (ks + 1 < ksteps){
      int kn = k0beg + (ks + 1) * 32;
      pa0 = *(const uint4*)(Ap0 + kn);
      pa1 = *(const uint4*)(Ap1 + kn);
      if (FID){ pl0 = *(const uint4*)(Ap0l + kn); pl1 = *(const uint4*)(Ap1l + kn); }
      if (bval){
        if (isf){
          #pragma unroll
          for (int i = 0; i < 8; i++){
            float2 v = *(const float2*)(Wf + ((long long)(kn + s_bk + i) * ldw + colOff0));
            pbf[i] = v.x; pbf[8 + i] = v.y;
          }
        } else {
          #pragma unroll
          for (int i = 0; i < 8; i++)
            pbb[i] = *(const u32*)(Wb + ((long long)(kn + s_bk + i) * ldw + colOff0));
        }
      }
    }
    __syncthreads();    // staging visible
    // ---- MFMA phase ----
    short8 ah[4], al4[4];
    #pragma unroll
    for (int mt = 0; mt < 4; mt++)
      ah[mt] = *(const short8*)&Ah[wr * 64 + mt * 16 + (ln & 15)][(ln >> 4) * 8];
    if (FID){
      #pragma unroll
      for (int mt = 0; mt < 4; mt++)
        al4[mt] = *(const short8*)&Al[wr * 64 + mt * 16 + (ln & 15)][(ln >> 4) * 8];
    }
    #pragma unroll
    for (int nt = 0; nt < 4; nt++){
      short8 bh = *(const short8*)&Bh[wc * 64 + nt * 16 + (ln & 15)][(ln >> 4) * 8];
      #pragma unroll
      for (int mt = 0; mt < 4; mt++)
        acc[mt][nt] = __builtin_amdgcn_mfma_f32_16x16x32_bf16(ah[mt], bh, acc[mt][nt], 0, 0, 0);
      if (FID){
        #pragma unroll
        for (int mt = 0; mt < 4; mt++)
          acc[mt][nt] = __builtin_amdgcn_mfma_f32_16x16x32_bf16(al4[mt], bh, acc[mt][nt], 0, 0, 0);
        if (isf){
          short8 bl = *(const short8*)&Bl[wc * 64 + nt * 16 + (ln & 15)][(ln >> 4) * 8];
          #pragma unroll
          for (int mt = 0; mt < 4; mt++)
            acc[mt][nt] = __builtin_amdgcn_mfma_f32_16x16x32_bf16(ah[mt], bl, acc[mt][nt], 0, 0, 0);
        }
      }
    }
  }

  // ---- epilogue ----
  int rl = (ln >> 4) * 4;
  int cl = ln & 15;
  bool doL = (lt != nullptr) && (blockIdx.z == 0);
  #pragma unroll
  for (int nt = 0; nt < 4; nt++){
    int gn = n0 + wc * 64 + nt * 16 + cl;
    if (gn >= N) continue;
    #pragma unroll
    for (int mt = 0; mt < 4; mt++){
      int gmb = m0 + wr * 64 + mt * 16 + rl;
      #pragma unroll
      for (int i = 0; i < 4; i++){
        int gm = gmb + i;
        float c = acc[mt][nt][i];
        if (mode == 2){
          float w = ew8[(size_t)gm * 8 + eIdx];
          if (w != 0.f){
            if (doL){
              const float* tr = lt + (size_t)gm * ldt;
              float l = 0.f;
              #pragma unroll
              for (int r = 0; r < 16; r++)
                l = fmaf(tr[r], ldin(lB, (size_t)(lbOff + (long long)r * ldlB + gn), isf), l);
              c += 2.0f * l;   // SCALING = 2.0
            }
            atomicAdd(&Cf[(size_t)gm * ldc + gn], c * w);
          }
        } else {
          if (doL){
            const float* tr = lt + (size_t)gm * ldt;
            float l = 0.f;
            #pragma unroll
            for (int r = 0; r < 16; r++)
              l = fmaf(tr[r], ldin(lB, (size_t)(lbOff + (long long)r * ldlB + gn), isf), l);
            c += 2.0f * l;
          }
          size_t ci = (size_t)gm * ldc + gn;
          if (mode == 0) Cb[ci] = __float2bfloat16(c);
          else Cf[ci] = c;
        }
      }
    }
  }
}

// ---------------- t2 = sr @ a2[e]  (per-row reduction, [NH][16] f32) ----------------
__global__ __launch_bounds__(256) void t2_k(const int* __restrict__ flagp,
    const bf16* __restrict__ sr, const void* __restrict__ a2, long long aOff,
    float* __restrict__ t2)
{
  int isf = flagp[0];
  int row = blockIdx.x;
  int tid = threadIdx.x;
  int wv = tid >> 6, ln = tid & 63;
  const bf16* srow = sr + (size_t)row * DFF;
  float acc[16];
  #pragma unroll
  for (int r = 0; r < 16; r++) acc[r] = 0.f;
  for (int kb = tid * 8; kb < DFF; kb += 2048){
    short8 v8 = *(const short8*)(srow + kb);
    #pragma unroll
    for (int j = 0; j < 8; j++){
      float v = bu2f((u16)v8[j]);
      #pragma unroll
      for (int r = 0; r < 16; r++)
        acc[r] = fmaf(v, ldin(a2, (size_t)(aOff + (long long)(kb + j) * 16 + r), isf), acc[r]);
    }
  }
  __shared__ float part[4][16];
  #pragma unroll
  for (int r = 0; r < 16; r++){
    float v = acc[r];
    #pragma unroll
    for (int of = 32; of; of >>= 1) v += __shfl_xor(v, of);
    if (ln == 0) part[wv][r] = v;
  }
  __syncthreads();
  if (tid < 16) t2[(size_t)row * 16 + tid] = part[0][tid] + part[1][tid] + part[2][tid] + part[3][tid];
}

// ---------------- RoPE (f32, in place) ----------------
__global__ void rope_f32(const int* __restrict__ flagp, float* __restrict__ x,
                         const void* __restrict__ cosb, const void* __restrict__ sinb, int nHd){
  int isf = flagp[0];
  int idx = blockIdx.x * 256 + threadIdx.x;
  int d = idx & 63; int t = idx >> 6;
  int hh = t % nHd; t /= nHd;
  int s = t & 1023; int b = t >> 10;
  if (b >= 2) return;
  float* p = x + (((size_t)(b * 1024 + s)) * nHd + hh) * 128;
  float x1 = p[d], x2 = p[d + 64];
  float c1 = ldin(cosb, (size_t)s * 128 + d, isf);
  float s1 = ldin(sinb, (size_t)s * 128 + d, isf);
  float c2 = ldin(cosb, (size_t)s * 128 + d + 64, isf);
  float s2 = ldin(sinb, (size_t)s * 128 + d + 64, isf);
  p[d]      = x1 * c1 - x2 * s1;
  p[d + 64] = x2 * c2 + x1 * s2;
}

// ---------------- Flash attention, f32, causal, GQA; writes split-bf16 output ----
__global__ __launch_bounds__(256) void flash_attn(const float* __restrict__ xq, const float* __restrict__ xk,
                                                  const float* __restrict__ xv,
                                                  bf16* __restrict__ ohi, bf16* __restrict__ olo){
  __shared__ float TA[64][65];   // d 0..63   (K then V)
  __shared__ float TB[64][65];   // d 64..127
  __shared__ float qsh[16][128];
  int bid = blockIdx.x;
  int qb = bid & 63, h = (bid >> 6) & 15, b = bid >> 10;
  int q0 = qb * 16, kvh = h >> 1;
  int tid = threadIdx.x, wv = tid >> 6, ln = tid & 63;
  {
    int r = tid >> 4, d0 = (tid & 15) * 8;
    const float* src = xq + ((size_t)((b * 1024 + q0 + r) * 16 + h)) * 128 + d0;
    const float sc = 0.08838834764831845f;  // 1/sqrt(128)
    #pragma unroll
    for (int j = 0; j < 8; j++) qsh[r][d0 + j] = src[j] * sc;
  }
  float mr[4] = {-1e30f, -1e30f, -1e30f, -1e30f};
  float lr[4] = {0, 0, 0, 0}, o0[4] = {0, 0, 0, 0}, o1[4] = {0, 0, 0, 0};
  int r0 = wv * 4;
  int ntiles = q0 / 64 + 1;
  for (int t = 0; t < ntiles; t++){
    __syncthreads();
    {
      int j = tid >> 2, dc = (tid & 3) * 16;
      const float* ks = xk + ((size_t)((b * 1024 + t * 64 + j) * 8 + kvh)) * 128 + dc;
      #pragma unroll
      for (int i = 0; i < 16; i++){ TA[j][dc + i] = ks[i]; TB[j][dc + i] = ks[64 + i]; }
    }
    __syncthreads();
    float s0 = 0, s1 = 0, s2 = 0, s3 = 0;
    for (int d = 0; d < 64; d++){
      float kv = TA[ln][d];
      s0 = fmaf(qsh[r0][d], kv, s0);     s1 = fmaf(qsh[r0 + 1][d], kv, s1);
      s2 = fmaf(qsh[r0 + 2][d], kv, s2); s3 = fmaf(qsh[r0 + 3][d], kv, s3);
    }
    for (int d = 0; d < 64; d++){
      float kv = TB[ln][d];
      s0 = fmaf(qsh[r0][d + 64], kv, s0);     s1 = fmaf(qsh[r0 + 1][d + 64], kv, s1);
      s2 = fmaf(qsh[r0 + 2][d + 64], kv, s2); s3 = fmaf(qsh[r0 + 3][d + 64], kv, s3);
    }
    int key = t * 64 + ln;
    float sv[4] = {s0, s1, s2, s3};
    float pv4[4];
    #pragma unroll
    for (int rr = 0; rr < 4; rr++){
      int q = q0 + r0 + rr;
      float s = (key <= q) ? sv[rr] : -1e30f;
      float mt = s;
      #pragma unroll
      for (int of = 32; of; of >>= 1) mt = fmaxf(mt, __shfl_xor(mt, of));
      float mnew = fmaxf(mr[rr], mt);
      float p = __expf(s - mnew);
      float alpha = __expf(mr[rr] - mnew);
      float ps = p;
      #pragma unroll
      for (int of = 32; of; of >>= 1) ps += __shfl_xor(ps, of);
      lr[rr] = lr[rr] * alpha + ps; mr[rr] = mnew;
      o0[rr] *= alpha; o1[rr] *= alpha;
      pv4[rr] = p;
    }
    __syncthreads();
    {
      int j = tid >> 2, dc = (tid & 3) * 16;
      const float* vs = xv + ((size_t)((b * 1024 + t * 64 + j) * 8 + kvh)) * 128 + dc;
      #pragma unroll
      for (int i = 0; i < 16; i++){ TA[j][dc + i] = vs[i]; TB[j][dc + i] = vs[64 + i]; }
    }
    __syncthreads();
    for (int j = 0; j < 64; j++){
      float va = TA[j][ln], vb = TB[j][ln];
      float p0 = __shfl(pv4[0], j), p1 = __shfl(pv4[1], j);
      float p2 = __shfl(pv4[2], j), p3 = __shfl(pv4[3], j);
      o0[0] = fmaf(p0, va, o0[0]); o1[0] = fmaf(p0, vb, o1[0]);
      o0[1] = fmaf(p1, va, o0[1]); o1[1] = fmaf(p1, vb, o1[1]);
      o0[2] = fmaf(p2, va, o0[2]); o1[2] = fmaf(p2, vb, o1[2]);
      o0[3] = fmaf(p3, va, o0[3]); o1[3] = fmaf(p3, vb, o1[3]);
    }
  }
  #pragma unroll
  for (int rr = 0; rr < 4; rr++){
    int q = q0 + r0 + rr;
    float inv = 1.0f / lr[rr];
    size_t ob = ((size_t)(b * 1024 + q)) * 2048 + (size_t)h * 128;
    float v0 = o0[rr] * inv, v1 = o1[rr] * inv;
    bf16 h0 = __float2bfloat16(v0), h1 = __float2bfloat16(v1);
    ohi[ob + ln] = h0;      olo[ob + ln]      = __float2bfloat16(v0 - __bfloat162float(h0));
    ohi[ob + ln + 64] = h1; olo[ob + ln + 64] = __float2bfloat16(v1 - __bfloat162float(h1));
  }
}

// ---------------- small elementwise kernels ----------------
__global__ void resid_k(const int* __restrict__ flagp, const void* __restrict__ data,
                        const float* __restrict__ proj, float* __restrict__ d2, int n){
  int isf = flagp[0];
  int i = blockIdx.x * 256 + threadIdx.x;
  if (i >= n) return;
  d2[i] = ldin(data, i, isf) + proj[i];
}

__global__ void final_k(const int* __restrict__ flagp, const float* __restrict__ d2,
                        const float* __restrict__ moe, void* __restrict__ out, int n){
  int isf = flagp[0];
  int i = blockIdx.x * 256 + threadIdx.x;
  if (i >= n) return;
  float v = d2[i] + moe[i];
  if (isf) ((float*)out)[i] = v;
  else ((bf16*)out)[i] = __float2bfloat16(v);
}

// ---------------- dense per-row SwiGLU with LoRA deltas for expert e ----------------
__global__ __launch_bounds__(256) void sr_k(
    const int* __restrict__ flagp,
    const bf16* __restrict__ cw1, const bf16* __restrict__ cw3,
    const float* __restrict__ t1, const float* __restrict__ t3,
    const void* __restrict__ b1, const void* __restrict__ b3,
    int r0, int e, bf16* __restrict__ srh)
{
  int isf = flagp[0];
  int s = blockIdx.y;
  int col0 = blockIdx.x * 256;
  int tid = threadIdx.x;
  int row = r0 + s;
  __shared__ float sb1[16][256], sb3[16][256];
  __shared__ float st1[16], st3[16];
  for (int idx = tid; idx < 16 * 256; idx += 256){
    int r = idx >> 8; int c = idx & 255;
    sb1[r][c] = ldin(b1, ((size_t)e * 16 + r) * DFF + col0 + c, isf);
    sb3[r][c] = ldin(b3, ((size_t)e * 16 + r) * DFF + col0 + c, isf);
  }
  if (tid < 16){
    st1[tid] = t1[(size_t)row * 128 + e * 16 + tid];
    st3[tid] = t3[(size_t)row * 128 + e * 16 + tid];
  }
  __syncthreads();
  int j = col0 + tid;
  float x1 = __bfloat162float(cw1[(size_t)s * DFF + j]);
  float x3 = __bfloat162float(cw3[(size_t)s * DFF + j]);
  float l1 = 0.f, l3 = 0.f;
  #pragma unroll
  for (int r = 0; r < 16; r++){
    l1 = fmaf(st1[r], sb1[r][tid], l1);
    l3 = fmaf(st3[r], sb3[r][tid], l3);
  }
  x1 += 2.0f * l1; x3 += 2.0f * l3;
  float sig = 1.0f / (1.0f + __expf(-x1));
  srh[(size_t)s * DFF + j] = __float2bfloat16(x1 * sig * x3);
}

// ---------------- host ----------------
extern "C" void kernel_launch(void* const* d_in, const int* in_sizes, int n_in,
                              void* d_out, int out_size, void* d_ws, size_t ws_size,
                              hipStream_t stream) {
  (void)in_sizes; (void)n_in;
  const void* data   = d_in[0];
  const void* cosb   = d_in[2];
  const void* sinb   = d_in[3];
  const void* attn_w = d_in[4];
  const void* ffn_w  = d_in[5];
  const void* wq = d_in[6];
  const void* wk = d_in[7];
  const void* wvw = d_in[8];
  const void* wo = d_in[9];
  const void* qa = d_in[10];
  const void* qb = d_in[11];
  const void* ka = d_in[12];
  const void* kb = d_in[13];
  const void* va = d_in[14];
  const void* vb = d_in[15];
  const void* oa = d_in[16];
  const void* ob = d_in[17];
  const void* gate_w = d_in[18];
  const void* w1 = d_in[19];
  const void* w2 = d_in[20];
  const void* w3 = d_in[21];
  const void* a1 = d_in[22];
  const void* b1 = d_in[23];
  const void* a3 = d_in[24];
  const void* b3 = d_in[25];
  const void* a2 = d_in[26];
  const void* b2 = d_in[27];

  const int nElem = NT * DMODEL;
  dim3 blk(256);

  size_t need = ((size_t)81 << 20);
  if (ws_size < need){
    fill_b<<<(out_size + 255) / 256, blk, 0, stream>>>((bf16*)d_out,
        1000.0f + (float)(ws_size >> 20), out_size);
    return;
  }
  char* base = (char*)d_ws;
  float* data2 = (float*)(base);                       // [0,16) MB, persists
  float* accb  = (float*)(base + ((size_t)16 << 20));  // [16,32): attn proj -> moe acc
  bf16*  h_hi  = (bf16*)(base + ((size_t)32 << 20));   // [32,40): h hi -> o hi -> sn
  bf16*  h_lo  = (bf16*)(base + ((size_t)40 << 20));   // [40,48): h lo -> o lo -> phase-B smalls
  float* xq = (float*)(base + ((size_t)48 << 20));     // [48,64)
  float* xk = (float*)(base + ((size_t)64 << 20));     // [64,72)
  float* xv = (float*)(base + ((size_t)72 << 20));     // [72,80)
  int*   flag = (int*)(base + ((size_t)80 << 20));     // [80,80+4)
  // tq..to2 live in data2's last 1 MB (data2 written only after their last use)
  float* tq  = (float*)(base + ((size_t)15 << 20));
  float* tk  = tq + (size_t)NT * 16;
  float* tv  = tk + (size_t)NT * 16;
  float* to2 = tv + (size_t)NT * 16;
  // phase-B smalls in h_lo region
  float* t1 = (float*)(base + ((size_t)40 << 20));     // NT*128 f32 = 1 MB
  float* t3 = t1 + (size_t)NT * 128;                   // 1 MB
  float* logits = t3 + (size_t)NT * 128;               // 64 KB
  float* ew = logits + NT * 8;                         // 64 KB
  float* t2h = ew + NT * 8;                            // NH*16 f32 = 32 KB
  // phase-B big (reuse xq/xk/xv region)
  bf16* cw1h = (bf16*)(base + ((size_t)48 << 20));     // NH*DFF bf16 = 8 MB
  bf16* cw3h = (bf16*)(base + ((size_t)56 << 20));     // 8 MB
  bf16* srh  = (bf16*)(base + ((size_t)64 << 20));     // 8 MB
  bf16* sn = h_hi;

  detect_k<<<1, 64, 0, stream>>>(cosb, flag);

  // ---- attention block (fidelity via hi/lo split) ----
  rmsnorm_split<<<NT, blk, 0, stream>>>(flag, data, attn_w, h_hi, h_lo);
  gemm128_t<1><<<dim3(16,1,1), blk, 0, stream>>>(flag, h_hi, h_lo, 2048, qa, 0, 16, 16,
      tq, nullptr, 16, NT, 16, 2048, nullptr, 0, nullptr, 0, 0, nullptr, 0, 1);
  gemm128_t<1><<<dim3(16,1,1), blk, 0, stream>>>(flag, h_hi, h_lo, 2048, ka, 0, 16, 16,
      tk, nullptr, 16, NT, 16, 2048, nullptr, 0, nullptr, 0, 0, nullptr, 0, 1);
  gemm128_t<1><<<dim3(16,1,1), blk, 0, stream>>>(flag, h_hi, h_lo, 2048, va, 0, 16, 16,
      tv, nullptr, 16, NT, 16, 2048, nullptr, 0, nullptr, 0, 0, nullptr, 0, 1);
  gemm128_t<1><<<dim3(16,16,1), blk, 0, stream>>>(flag, h_hi, h_lo, 2048, wq, 0, 2048, 16,
      xq, nullptr, 2048, NT, 2048, 2048, tq, 16, qb, 0, 2048, nullptr, 0, 1);
  gemm128_t<1><<<dim3(16,8,1), blk, 0, stream>>>(flag, h_hi, h_lo, 2048, wk, 0, 1024, 16,
      xk, nullptr, 1024, NT, 1024, 2048, tk, 16, kb, 0, 1024, nullptr, 0, 1);
  gemm128_t<1><<<dim3(16,8,1), blk, 0, stream>>>(flag, h_hi, h_lo, 2048, wvw, 0, 1024, 16,
      xv, nullptr, 1024, NT, 1024, 2048, tv, 16, vb, 0, 1024, nullptr, 0, 1);
  rope_f32<<<8192, blk, 0, stream>>>(flag, xq, cosb, sinb, 16);
  rope_f32<<<4096, blk, 0, stream>>>(flag, xk, cosb, sinb, 8);
  flash_attn<<<2048, blk, 0, stream>>>(xq, xk, xv, h_hi, h_lo);   // o -> h_hi/h_lo
  gemm128_t<1><<<dim3(16,1,1), blk, 0, stream>>>(flag, h_hi, h_lo, 2048, oa, 0, 16, 16,
      to2, nullptr, 16, NT, 16, 2048, nullptr, 0, nullptr, 0, 0, nullptr, 0, 1);
  gemm128_t<1><<<dim3(16,16,1), blk, 0, stream>>>(flag, h_hi, h_lo, 2048, wo, 0, 2048, 16,
      accb, nullptr, 2048, NT, 2048, 2048, to2, 16, ob, 0, 2048, nullptr, 0, 1);
  resid_k<<<(nElem + 255) / 256, blk, 0, stream>>>(flag, data, accb, data2, nElem);

  // ---- MoE prep ----
  rmsnorm_f32<<<NT, blk, 0, stream>>>(flag, data2, ffn_w, sn);
  logits_k<<<NT, blk, 0, stream>>>(flag, data2, ffn_w, gate_w, logits);
  route_ew<<<8, blk, 0, stream>>>(logits, ew);
  zero_f<<<(nElem + 255) / 256, blk, 0, stream>>>(accb, nElem);
  // all-expert LoRA t-projections in one launch each (a1/a3 are [E][D][16])
  gemm128_t<0><<<dim3(16,1,1), blk, 0, stream>>>(flag, sn, nullptr, 2048, a1, 0, 16, 2048LL*16,
      t1, nullptr, 128, NT, 128, 2048, nullptr, 0, nullptr, 0, 0, nullptr, 0, 1);
  gemm128_t<0><<<dim3(16,1,1), blk, 0, stream>>>(flag, sn, nullptr, 2048, a3, 0, 16, 2048LL*16,
      t3, nullptr, 128, NT, 128, 2048, nullptr, 0, nullptr, 0, 0, nullptr, 0, 1);

  // ---- dense MoE in 4 quarters of NH=512 rows ----
  for (int hf = 0; hf < 4; hf++){
    int r0 = hf * NH;
    gemm128_t<0><<<dim3(4,64,1), blk, 0, stream>>>(flag, sn + (size_t)r0 * 2048, nullptr, 2048,
        w1, 0, 8192, 16, nullptr, cw1h, 8192, NH, 8192, 2048,
        nullptr, 0, nullptr, 0, 0, nullptr, 0, 0);
    gemm128_t<0><<<dim3(4,64,1), blk, 0, stream>>>(flag, sn + (size_t)r0 * 2048, nullptr, 2048,
        w3, 0, 8192, 16, nullptr, cw3h, 8192, NH, 8192, 2048,
        nullptr, 0, nullptr, 0, 0, nullptr, 0, 0);
    for (int e = 0; e < 8; e++){
      sr_k<<<dim3(32, NH), blk, 0, stream>>>(flag, cw1h, cw3h, t1, t3, b1, b3, r0, e, srh);
      t2_k<<<NH, blk, 0, stream>>>(flag, srh, a2, (long long)e * DFF * 16, t2h);
      gemm128_t<0><<<dim3(4,16,4), blk, 0, stream>>>(flag, srh, nullptr, 8192,
          w2, 0, 2048, 16, accb + (size_t)r0 * 2048, nullptr, 2048, NH, 2048, 8192,
          t2h, 16, b2, (long long)e * 16 * 2048, 2048, ew + (size_t)r0 * 8, e, 2);
    }
  }
  final_k<<<(nElem + 255) / 256, blk, 0, stream>>>(flag, data2, accb, d_out, nElem);
}

// Round 4
// 10006.665 us; speedup vs baseline: 2.3307x; 1.4749x over previous
//
#include <hip/hip_runtime.h>
#include <hip/hip_bf16.h>
#include <cstdint>

// MixTransformer: B=2,S=1024,D=2048,H=16,KVH=8,HD=128,DFF=8192,E=8,K=2,R=16
// Round 8: resubmit of Round-7 (infra failure, no counters; audit found no
// crash vector — precedent R1->R2 cleared identically). Token-gather sparse
// MoE: per quarter exactly 1024 (token,expert) pairs packed by expert
// (build_k); sr_pack writes packed SwiGLU rows; ONE gemm_w2 dispatch
// (z=expert) computes only assigned rows with scatter-atomicAdd + fused
// b2-LoRA epilogue. w2 FLOPs 550->137 GF. Split-K mode 3 for N<=128 projs.

typedef __hip_bfloat16 bf16;
typedef unsigned short u16;
typedef unsigned int u32;
typedef __attribute__((ext_vector_type(8))) short short8;
typedef __attribute__((ext_vector_type(4))) float floatx4;

#define NT 2048      // B*S
#define DMODEL 2048
#define DFF 8192
#define NH 512       // rows per MoE quarter-batch
#define NPAIR 1024   // NH * K(=2) pairs per quarter

__device__ __forceinline__ float ldin(const void* p, size_t i, int isf){
  return isf ? ((const float*)p)[i] : __bfloat162float(((const bf16*)p)[i]);
}
__device__ __forceinline__ u16 f2bu(float v){ bf16 h = __float2bfloat16(v); return *(u16*)&h; }
__device__ __forceinline__ float bu2f(u16 v){ u32 x = ((u32)v) << 16; return __uint_as_float(x); }
__device__ __forceinline__ u32 pk2(u16 a, u16 b){ return (u32)a | ((u32)b << 16); }

// ---------------- dtype detection: cos[0] == 1.0f ----------------
__global__ void detect_k(const void* __restrict__ cosp, int* __restrict__ flag){
  if (threadIdx.x == 0 && blockIdx.x == 0){
    u32 w = *(const u32*)cosp;
    flag[0] = (w == 0x3F800000u) ? 1 : 0;   // 1 = float32 inputs, 0 = bf16
  }
}

// ---------------- RMSNorm producing hi/lo bf16 split ----------------
__global__ __launch_bounds__(256) void rmsnorm_split(const int* __restrict__ flagp,
                                                     const void* __restrict__ x, const void* __restrict__ w,
                                                     bf16* __restrict__ hi, bf16* __restrict__ lo){
  int isf = flagp[0];
  int row = blockIdx.x; int tid = threadIdx.x;
  float ss = 0.f;
  for (int d = tid; d < DMODEL; d += 256){ float v = ldin(x, (size_t)row * DMODEL + d, isf); ss = fmaf(v, v, ss); }
  __shared__ float red[256];
  red[tid] = ss; __syncthreads();
  for (int s = 128; s > 0; s >>= 1){ if (tid < s) red[tid] += red[tid + s]; __syncthreads(); }
  float m = red[0] / (float)DMODEL + 1e-5f;
  float r = rsqrtf(m); r = r * (1.5f - 0.5f * m * r * r);  // Newton refine
  for (int d = tid; d < DMODEL; d += 256){
    float v = ldin(x, (size_t)row * DMODEL + d, isf) * r * ldin(w, d, isf);
    bf16 vh = __float2bfloat16(v);
    hi[(size_t)row * DMODEL + d] = vh;
    lo[(size_t)row * DMODEL + d] = __float2bfloat16(v - __bfloat162float(vh));
  }
}

// ---------------- RMSNorm f32 -> bf16 ----------------
__global__ __launch_bounds__(256) void rmsnorm_f32(const int* __restrict__ flagp,
                                                   const float* __restrict__ x, const void* __restrict__ w,
                                                   bf16* __restrict__ out){
  int isf = flagp[0];
  int row = blockIdx.x; int tid = threadIdx.x;
  const float* xr = x + (size_t)row * DMODEL;
  float ss = 0.f;
  for (int d = tid; d < DMODEL; d += 256){ float v = xr[d]; ss = fmaf(v, v, ss); }
  __shared__ float red[256];
  red[tid] = ss; __syncthreads();
  for (int s = 128; s > 0; s >>= 1){ if (tid < s) red[tid] += red[tid + s]; __syncthreads(); }
  float m = red[0] / (float)DMODEL + 1e-5f;
  float r = rsqrtf(m); r = r * (1.5f - 0.5f * m * r * r);
  for (int d = tid; d < DMODEL; d += 256)
    out[(size_t)row * DMODEL + d] = __float2bfloat16(xr[d] * r * ldin(w, d, isf));
}

// ---------------- Gate logits in f64 (routing precision) ----------------
__global__ __launch_bounds__(256) void logits_k(const int* __restrict__ flagp,
                                                const float* __restrict__ x, const void* __restrict__ w,
                                                const void* __restrict__ gw, float* __restrict__ out){
  int isf = flagp[0];
  int row = blockIdx.x; int tid = threadIdx.x;
  const float* xr = x + (size_t)row * DMODEL;
  __shared__ double red[256];
  double ss = 0.0;
  for (int d = tid; d < DMODEL; d += 256){ double v = xr[d]; ss += v * v; }
  red[tid] = ss; __syncthreads();
  for (int s = 128; s > 0; s >>= 1){ if (tid < s) red[tid] += red[tid + s]; __syncthreads(); }
  double scale = 1.0 / sqrt(red[0] / (double)DMODEL + 1e-5);
  double acc[8] = {0,0,0,0,0,0,0,0};
  for (int d = tid; d < DMODEL; d += 256){
    double sv = (double)xr[d] * scale * (double)ldin(w, d, isf);
    #pragma unroll
    for (int e = 0; e < 8; e++) acc[e] += sv * (double)ldin(gw, (size_t)d * 8 + e, isf);
  }
  __shared__ double red8[256][8];
  #pragma unroll
  for (int e = 0; e < 8; e++) red8[tid][e] = acc[e];
  __syncthreads();
  for (int s = 128; s > 0; s >>= 1){
    if (tid < s){ for (int e = 0; e < 8; e++) red8[tid][e] += red8[tid + s][e]; }
    __syncthreads();
  }
  if (tid < 8) out[row * 8 + tid] = (float)red8[0][tid];
}

// ---------------- Routing -> dense ew[NT][8] (0 for unselected) ----------------
__global__ void route_ew(const float* __restrict__ logits, float* __restrict__ ew){
  int row = blockIdx.x * 256 + threadIdx.x;
  if (row >= NT) return;
  float l[8]; float mx = -1e30f;
  for (int e = 0; e < 8; e++){ l[e] = logits[row * 8 + e]; mx = fmaxf(mx, l[e]); }
  float p[8];
  for (int e = 0; e < 8; e++) p[e] = expf(l[e] - mx);
  int e1 = 0; float b1v = p[0];
  for (int e = 1; e < 8; e++) if (p[e] > b1v){ b1v = p[e]; e1 = e; }
  int e2 = -1; float b2v = -1.f;
  for (int e = 0; e < 8; e++) if (e != e1 && p[e] > b2v){ b2v = p[e]; e2 = e; }
  float s = b1v + b2v;
  for (int e = 0; e < 8; e++){
    float w = 0.f;
    if (e == e1) w = b1v / s;
    else if (e == e2) w = b2v / s;
    ew[row * 8 + e] = w;
  }
}

// ---------------- per-quarter (token,expert) pair lists, packed by expert ----
__global__ __launch_bounds__(512) void build_k(const float* __restrict__ ew, int r0,
                                               int* __restrict__ pidx, int* __restrict__ pexp,
                                               float* __restrict__ wgt, int* __restrict__ offp){
  __shared__ int cnt[8], cur[8], offs[9];
  int tid = threadIdx.x;
  if (tid < 8) cnt[tid] = 0;
  __syncthreads();
  int row = r0 + tid;
  int ea = -1, eb = -1; float wa = 0.f, wb = 0.f;
  for (int e = 0; e < 8; e++){
    float w = ew[(size_t)row * 8 + e];
    if (w != 0.f){ if (ea < 0){ ea = e; wa = w; } else { eb = e; wb = w; } }
  }
  if (ea < 0){ ea = 0; wa = 0.f; }          // defensive (cannot happen)
  if (eb < 0){ eb = ea; wb = 0.f; }
  atomicAdd(&cnt[ea], 1); atomicAdd(&cnt[eb], 1);
  __syncthreads();
  if (tid == 0){
    int s = 0;
    for (int e = 0; e < 8; e++){ offs[e] = s; s += cnt[e]; }
    offs[8] = s;
    for (int e = 0; e < 8; e++) cur[e] = offs[e];
  }
  __syncthreads();
  int pa = atomicAdd(&cur[ea], 1);
  pidx[pa] = row; pexp[pa] = ea; wgt[pa] = wa;
  int pb = atomicAdd(&cur[eb], 1);
  pidx[pb] = row; pexp[pb] = eb; wgt[pb] = wb;
  if (tid < 9) offp[tid] = offs[tid];
}

__global__ void zero_f(float* __restrict__ p, int n){
  int i = blockIdx.x * 256 + threadIdx.x;
  if (i < n) p[i] = 0.f;
}
__global__ void fill_b(bf16* __restrict__ p, float v, int n){
  int i = blockIdx.x * 256 + threadIdx.x;
  if (i < n) p[i] = __float2bfloat16(v);
}

// ---------------- 128x128-tile MFMA GEMM ----------------
// C = A@W (+fidelity passes) (+ 2*lt@lB LoRA epilogue)
// A,A2: bf16 [M][lda] (A2 = lo split when FID). W: f32 or bf16 by flag.
// W element (k,n) at: wOff + k*ldw + (n>>4)*wstride + (n&15)   (wstride=16 -> plain)
// FID: acc += Ahi*Whi + Alo*Whi (+ Ahi*Wlo when W is f32).
// mode 0: Cb=bf16(c); 1: Cf=c; 2: w=ew8[gm*8+eIdx]; if(w) atomicAdd(Cf, c*w);
// mode 3: atomicAdd(Cf, c)  [split-K accumulate; caller zero-inits]
// Split-K via gridDim.z; LoRA applied only on z==0 chunk.
// Requires M%128==0, Kd%(32*gridDim.z)==0. N guarded (OOB cols stage zeros).
template<int FID>
__global__ __launch_bounds__(256) void gemm128_t(
    const int* __restrict__ flagp,
    const bf16* __restrict__ A, const bf16* __restrict__ A2, int lda,
    const void* __restrict__ W, long long wOff, int ldw, long long wstride,
    float* __restrict__ Cf, bf16* __restrict__ Cb, int ldc,
    int M, int N, int Kd,
    const float* __restrict__ lt, int ldt,
    const void* __restrict__ lB, long long lbOff, int ldlB,
    const float* __restrict__ ew8, int eIdx, int mode)
{
  int isf = flagp[0];
  int m0 = blockIdx.x * 128;
  int n0 = blockIdx.y * 128;
  if (m0 >= M) return;
  int nz = gridDim.z;
  int ksteps = (Kd >> 5) / nz;
  int k0beg = blockIdx.z * ksteps * 32;

  __shared__ __align__(16) u16 Ah[128][32];                 // 8 KB, linear 64B rows
  __shared__ __align__(16) u16 Bh[128][40];                 // 10 KB, [n][k], pad->aligned b128
  __shared__ __align__(16) u16 Al[FID ? 128 : 1][32];
  __shared__ __align__(16) u16 Bl[FID ? 128 : 1][40];

  int tid = threadIdx.x;
  int wv = tid >> 6, ln = tid & 63;
  int wr = wv >> 1, wc = wv & 1;

  // A staging: rows s_ar, s_ar+64; 8-elem chunk s_ac (coalesced: 4 lanes = 64B row)
  int s_ar = tid >> 2;
  int s_ac = (tid & 3) * 8;
  const bf16* Ap0 = A + (size_t)(m0 + s_ar) * lda + s_ac;
  const bf16* Ap1 = A + (size_t)(m0 + s_ar + 64) * lda + s_ac;
  const bf16* Ap0l = Ap0; const bf16* Ap1l = Ap1;
  if (FID){ Ap0l = A2 + (size_t)(m0 + s_ar) * lda + s_ac; Ap1l = A2 + (size_t)(m0 + s_ar + 64) * lda + s_ac; }

  // B staging: col pair (s_bn, s_bn+1), k-octet s_bk
  int s_bn = (tid & 63) * 2;
  int s_bk = (tid >> 6) * 8;
  int gn0 = n0 + s_bn;
  bool bval = gn0 < N;
  long long colOff0 = wOff + (long long)(gn0 >> 4) * wstride + (gn0 & 15);
  const float* Wf = (const float*)W;
  const bf16*  Wb = (const bf16*)W;

  floatx4 acc[4][4];
  #pragma unroll
  for (int a = 0; a < 4; a++)
    #pragma unroll
    for (int b = 0; b < 4; b++) acc[a][b] = (floatx4){0.f, 0.f, 0.f, 0.f};

  uint4 pa0 = {0,0,0,0}, pa1 = {0,0,0,0}, pl0 = {0,0,0,0}, pl1 = {0,0,0,0};
  float pbf[16];
  u32 pbb[8];
  #pragma unroll
  for (int i = 0; i < 16; i++) pbf[i] = 0.f;
  #pragma unroll
  for (int i = 0; i < 8; i++) pbb[i] = 0;

  // prefetch first K-tile
  pa0 = *(const uint4*)(Ap0 + k0beg);
  pa1 = *(const uint4*)(Ap1 + k0beg);
  if (FID){ pl0 = *(const uint4*)(Ap0l + k0beg); pl1 = *(const uint4*)(Ap1l + k0beg); }
  if (bval){
    if (isf){
      #pragma unroll
      for (int i = 0; i < 8; i++){
        float2 v = *(const float2*)(Wf + ((long long)(k0beg + s_bk + i) * ldw + colOff0));
        pbf[i] = v.x; pbf[8 + i] = v.y;
      }
    } else {
      #pragma unroll
      for (int i = 0; i < 8; i++)
        pbb[i] = *(const u32*)(Wb + ((long long)(k0beg + s_bk + i) * ldw + colOff0));
    }
  }

  for (int ks = 0; ks < ksteps; ks++){
    __syncthreads();    // previous iteration's fragment reads complete
    // ---- commit staged tile to LDS ----
    *(uint4*)&Ah[s_ar][s_ac] = pa0;
    *(uint4*)&Ah[s_ar + 64][s_ac] = pa1;
    if (FID){
      *(uint4*)&Al[s_ar][s_ac] = pl0;
      *(uint4*)&Al[s_ar + 64][s_ac] = pl1;
    }
    {
      u16 h[16], l[16];
      if (bval && isf){
        #pragma unroll
        for (int i = 0; i < 16; i++){ h[i] = f2bu(pbf[i]); l[i] = f2bu(pbf[i] - bu2f(h[i])); }
      } else if (bval){
        #pragma unroll
        for (int i = 0; i < 8; i++){ h[i] = (u16)(pbb[i] & 0xffff); h[8 + i] = (u16)(pbb[i] >> 16); l[i] = 0; l[8 + i] = 0; }
      } else {
        #pragma unroll
        for (int i = 0; i < 16; i++){ h[i] = 0; l[i] = 0; }
      }
      uint4 H0, H1;
      H0.x = pk2(h[0], h[1]);  H0.y = pk2(h[2], h[3]);  H0.z = pk2(h[4], h[5]);  H0.w = pk2(h[6], h[7]);
      H1.x = pk2(h[8], h[9]);  H1.y = pk2(h[10], h[11]); H1.z = pk2(h[12], h[13]); H1.w = pk2(h[14], h[15]);
      *(uint4*)&Bh[s_bn][s_bk]     = H0;
      *(uint4*)&Bh[s_bn + 1][s_bk] = H1;
      if (FID && isf){
        uint4 L0, L1;
        L0.x = pk2(l[0], l[1]);  L0.y = pk2(l[2], l[3]);  L0.z = pk2(l[4], l[5]);  L0.w = pk2(l[6], l[7]);
        L1.x = pk2(l[8], l[9]);  L1.y = pk2(l[10], l[11]); L1.z = pk2(l[12], l[13]); L1.w = pk2(l[14], l[15]);
        *(uint4*)&Bl[s_bn][s_bk]     = L0;
        *(uint4*)&Bl[s_bn + 1][s_bk] = L1;
      }
    }
    // ---- issue next K-tile loads (latency hides under MFMA phase) ----
    if (ks + 1 < ksteps){
      int kn = k0beg + (ks + 1) * 32;
      pa0 = *(const uint4*)(Ap0 + kn);
      pa1 = *(const uint4*)(Ap1 + kn);
      if (FID){ pl0 = *(const uint4*)(Ap0l + kn); pl1 = *(const uint4*)(Ap1l + kn); }
      if (bval){
        if (isf){
          #pragma unroll
          for (int i = 0; i < 8; i++){
            float2 v = *(const float2*)(Wf + ((long long)(kn + s_bk + i) * ldw + colOff0));
            pbf[i] = v.x; pbf[8 + i] = v.y;
          }
        } else {
          #pragma unroll
          for (int i = 0; i < 8; i++)
            pbb[i] = *(const u32*)(Wb + ((long long)(kn + s_bk + i) * ldw + colOff0));
        }
      }
    }
    __syncthreads();    // staging visible
    // ---- MFMA phase ----
    short8 ah[4], al4[4];
    #pragma unroll
    for (int mt = 0; mt < 4; mt++)
      ah[mt] = *(const short8*)&Ah[wr * 64 + mt * 16 + (ln & 15)][(ln >> 4) * 8];
    if (FID){
      #pragma unroll
      for (int mt = 0; mt < 4; mt++)
        al4[mt] = *(const short8*)&Al[wr * 64 + mt * 16 + (ln & 15)][(ln >> 4) * 8];
    }
    #pragma unroll
    for (int nt = 0; nt < 4; nt++){
      short8 bh = *(const short8*)&Bh[wc * 64 + nt * 16 + (ln & 15)][(ln >> 4) * 8];
      #pragma unroll
      for (int mt = 0; mt < 4; mt++)
        acc[mt][nt] = __builtin_amdgcn_mfma_f32_16x16x32_bf16(ah[mt], bh, acc[mt][nt], 0, 0, 0);
      if (FID){
        #pragma unroll
        for (int mt = 0; mt < 4; mt++)
          acc[mt][nt] = __builtin_amdgcn_mfma_f32_16x16x32_bf16(al4[mt], bh, acc[mt][nt], 0, 0, 0);
        if (isf){
          short8 bl = *(const short8*)&Bl[wc * 64 + nt * 16 + (ln & 15)][(ln >> 4) * 8];
          #pragma unroll
          for (int mt = 0; mt < 4; mt++)
            acc[mt][nt] = __builtin_amdgcn_mfma_f32_16x16x32_bf16(ah[mt], bl, acc[mt][nt], 0, 0, 0);
        }
      }
    }
  }

  // ---- epilogue ----
  int rl = (ln >> 4) * 4;
  int cl = ln & 15;
  bool doL = (lt != nullptr) && (blockIdx.z == 0);
  #pragma unroll
  for (int nt = 0; nt < 4; nt++){
    int gn = n0 + wc * 64 + nt * 16 + cl;
    if (gn >= N) continue;
    #pragma unroll
    for (int mt = 0; mt < 4; mt++){
      int gmb = m0 + wr * 64 + mt * 16 + rl;
      #pragma unroll
      for (int i = 0; i < 4; i++){
        int gm = gmb + i;
        float c = acc[mt][nt][i];
        if (mode == 2){
          float w = ew8[(size_t)gm * 8 + eIdx];
          if (w != 0.f){
            if (doL){
              const float* tr = lt + (size_t)gm * ldt;
              float l = 0.f;
              #pragma unroll
              for (int r = 0; r < 16; r++)
                l = fmaf(tr[r], ldin(lB, (size_t)(lbOff + (long long)r * ldlB + gn), isf), l);
              c += 2.0f * l;   // SCALING = 2.0
            }
            atomicAdd(&Cf[(size_t)gm * ldc + gn], c * w);
          }
        } else {
          if (doL){
            const float* tr = lt + (size_t)gm * ldt;
            float l = 0.f;
            #pragma unroll
            for (int r = 0; r < 16; r++)
              l = fmaf(tr[r], ldin(lB, (size_t)(lbOff + (long long)r * ldlB + gn), isf), l);
            c += 2.0f * l;
          }
          size_t ci = (size_t)gm * ldc + gn;
          if (mode == 0) Cb[ci] = __float2bfloat16(c);
          else if (mode == 1) Cf[ci] = c;
          else atomicAdd(&Cf[ci], c);          // mode 3
        }
      }
    }
  }
}

// ---------------- packed-A w2 GEMM: one dispatch covers all 8 experts ----------
// srp: packed [NPAIR][DFF] bf16 rows (by-expert segments via offp).
// grid (4, 16, 8): z = expert, x = m-block within segment, y = n-block.
// Epilogue: c += 2*t2p[p]@b2[e]; atomicAdd(accb[pidx[p]*2048+gn], c*wgt[p]).
__global__ __launch_bounds__(256) void gemm_w2(
    const int* __restrict__ flagp,
    const bf16* __restrict__ srp,
    const void* __restrict__ W,          // w2 [DFF][2048]
    const void* __restrict__ b2,         // [E][16][2048]
    const float* __restrict__ t2p,       // [NPAIR][16]
    const int* __restrict__ pidx, const float* __restrict__ wgt,
    const int* __restrict__ offp,        // [9]
    float* __restrict__ accb)
{
  int isf = flagp[0];
  int e = blockIdx.z;
  int off = offp[e];
  int cnt = offp[e + 1] - off;
  int m0 = blockIdx.x * 128;
  if (m0 >= cnt) return;
  int n0 = blockIdx.y * 128;

  __shared__ __align__(16) u16 Ah[128][32];
  __shared__ __align__(16) u16 Bh[128][40];

  int tid = threadIdx.x;
  int wv = tid >> 6, ln = tid & 63;
  int wr = wv >> 1, wc = wv & 1;

  int s_ar = tid >> 2;
  int s_ac = (tid & 3) * 8;
  int r0p = off + m0 + s_ar;            // packed row (clamped against buffer end)
  int r1p = r0p + 64;
  if (r0p > NPAIR - 1) r0p = NPAIR - 1;
  if (r1p > NPAIR - 1) r1p = NPAIR - 1;
  const bf16* Ap0 = srp + (size_t)r0p * DFF + s_ac;
  const bf16* Ap1 = srp + (size_t)r1p * DFF + s_ac;

  int s_bn = (tid & 63) * 2;
  int s_bk = (tid >> 6) * 8;
  int gn0 = n0 + s_bn;                  // < 2048 always
  const float* Wf = (const float*)W;
  const bf16*  Wb = (const bf16*)W;

  floatx4 acc[4][4];
  #pragma unroll
  for (int a = 0; a < 4; a++)
    #pragma unroll
    for (int b = 0; b < 4; b++) acc[a][b] = (floatx4){0.f, 0.f, 0.f, 0.f};

  uint4 pa0, pa1;
  float pbf[16];
  u32 pbb[8];

  pa0 = *(const uint4*)(Ap0);
  pa1 = *(const uint4*)(Ap1);
  if (isf){
    #pragma unroll
    for (int i = 0; i < 8; i++){
      float2 v = *(const float2*)(Wf + ((long long)(s_bk + i) * 2048 + gn0));
      pbf[i] = v.x; pbf[8 + i] = v.y;
    }
  } else {
    #pragma unroll
    for (int i = 0; i < 8; i++)
      pbb[i] = *(const u32*)(Wb + ((long long)(s_bk + i) * 2048 + gn0));
  }

  const int ksteps = DFF / 32;          // 256
  for (int ks = 0; ks < ksteps; ks++){
    __syncthreads();
    *(uint4*)&Ah[s_ar][s_ac] = pa0;
    *(uint4*)&Ah[s_ar + 64][s_ac] = pa1;
    {
      u16 h[16];
      if (isf){
        #pragma unroll
        for (int i = 0; i < 16; i++) h[i] = f2bu(pbf[i]);
      } else {
        #pragma unroll
        for (int i = 0; i < 8; i++){ h[i] = (u16)(pbb[i] & 0xffff); h[8 + i] = (u16)(pbb[i] >> 16); }
      }
      uint4 H0, H1;
      H0.x = pk2(h[0], h[1]);  H0.y = pk2(h[2], h[3]);  H0.z = pk2(h[4], h[5]);  H0.w = pk2(h[6], h[7]);
      H1.x = pk2(h[8], h[9]);  H1.y = pk2(h[10], h[11]); H1.z = pk2(h[12], h[13]); H1.w = pk2(h[14], h[15]);
      *(uint4*)&Bh[s_bn][s_bk]     = H0;
      *(uint4*)&Bh[s_bn + 1][s_bk] = H1;
    }
    if (ks + 1 < ksteps){
      int kn = (ks + 1) * 32;
      pa0 = *(const uint4*)(Ap0 + kn);
      pa1 = *(const uint4*)(Ap1 + kn);
      if (isf){
        #pragma unroll
        for (int i = 0; i < 8; i++){
          float2 v = *(const float2*)(Wf + ((long long)(kn + s_bk + i) * 2048 + gn0));
          pbf[i] = v.x; pbf[8 + i] = v.y;
        }
      } else {
        #pragma unroll
        for (int i = 0; i < 8; i++)
          pbb[i] = *(const u32*)(Wb + ((long long)(kn + s_bk + i) * 2048 + gn0));
      }
    }
    __syncthreads();
    short8 ah[4];
    #pragma unroll
    for (int mt = 0; mt < 4; mt++)
      ah[mt] = *(const short8*)&Ah[wr * 64 + mt * 16 + (ln & 15)][(ln >> 4) * 8];
    #pragma unroll
    for (int nt = 0; nt < 4; nt++){
      short8 bh = *(const short8*)&Bh[wc * 64 + nt * 16 + (ln & 15)][(ln >> 4) * 8];
      #pragma unroll
      for (int mt = 0; mt < 4; mt++)
        acc[mt][nt] = __builtin_amdgcn_mfma_f32_16x16x32_bf16(ah[mt], bh, acc[mt][nt], 0, 0, 0);
    }
  }

  // epilogue: scatter with fused b2-LoRA
  int rl = (ln >> 4) * 4;
  int cl = ln & 15;
  long long eOff = (long long)e * 16 * 2048;
  #pragma unroll
  for (int nt = 0; nt < 4; nt++){
    int gn = n0 + wc * 64 + nt * 16 + cl;
    #pragma unroll
    for (int mt = 0; mt < 4; mt++){
      int gmb = m0 + wr * 64 + mt * 16 + rl;
      #pragma unroll
      for (int i = 0; i < 4; i++){
        int gm = gmb + i;
        if (gm >= cnt) continue;
        int p = off + gm;
        const float* tr = t2p + (size_t)p * 16;
        float l = 0.f;
        #pragma unroll
        for (int r = 0; r < 16; r++)
          l = fmaf(tr[r], ldin(b2, (size_t)(eOff + (long long)r * 2048 + gn), isf), l);
        float c = acc[mt][nt][i] + 2.0f * l;
        atomicAdd(&accb[(size_t)pidx[p] * 2048 + gn], c * wgt[p]);
      }
    }
  }
}

// ---------------- t2p = srp @ a2[pexp]  (per-pair reduction, [NPAIR][16]) ------
__global__ __launch_bounds__(256) void t2_pack(const int* __restrict__ flagp,
    const bf16* __restrict__ srp, const void* __restrict__ a2,
    const int* __restrict__ pexp, float* __restrict__ t2p)
{
  int isf = flagp[0];
  int p = blockIdx.x;
  int tid = threadIdx.x;
  int wv = tid >> 6, ln = tid & 63;
  long long aOff = (long long)pexp[p] * DFF * 16;
  const bf16* srow = srp + (size_t)p * DFF;
  float acc[16];
  #pragma unroll
  for (int r = 0; r < 16; r++) acc[r] = 0.f;
  for (int kb = tid * 8; kb < DFF; kb += 2048){
    short8 v8 = *(const short8*)(srow + kb);
    #pragma unroll
    for (int j = 0; j < 8; j++){
      float v = bu2f((u16)v8[j]);
      #pragma unroll
      for (int r = 0; r < 16; r++)
        acc[r] = fmaf(v, ldin(a2, (size_t)(aOff + (long long)(kb + j) * 16 + r), isf), acc[r]);
    }
  }
  __shared__ float part[4][16];
  #pragma unroll
  for (int r = 0; r < 16; r++){
    float v = acc[r];
    #pragma unroll
    for (int of = 32; of; of >>= 1) v += __shfl_xor(v, of);
    if (ln == 0) part[wv][r] = v;
  }
  __syncthreads();
  if (tid < 16) t2p[(size_t)p * 16 + tid] = part[0][tid] + part[1][tid] + part[2][tid] + part[3][tid];
}

// ---------------- RoPE (f32, in place) ----------------
__global__ void rope_f32(const int* __restrict__ flagp, float* __restrict__ x,
                         const void* __restrict__ cosb, const void* __restrict__ sinb, int nHd){
  int isf = flagp[0];
  int idx = blockIdx.x * 256 + threadIdx.x;
  int d = idx & 63; int t = idx >> 6;
  int hh = t % nHd; t /= nHd;
  int s = t & 1023; int b = t >> 10;
  if (b >= 2) return;
  float* p = x + (((size_t)(b * 1024 + s)) * nHd + hh) * 128;
  float x1 = p[d], x2 = p[d + 64];
  float c1 = ldin(cosb, (size_t)s * 128 + d, isf);
  float s1 = ldin(sinb, (size_t)s * 128 + d, isf);
  float c2 = ldin(cosb, (size_t)s * 128 + d + 64, isf);
  float s2 = ldin(sinb, (size_t)s * 128 + d + 64, isf);
  p[d]      = x1 * c1 - x2 * s1;
  p[d + 64] = x2 * c2 + x1 * s2;
}

// ---------------- Flash attention, f32, causal, GQA; writes split-bf16 output ----
__global__ __launch_bounds__(256) void flash_attn(const float* __restrict__ xq, const float* __restrict__ xk,
                                                  const float* __restrict__ xv,
                                                  bf16* __restrict__ ohi, bf16* __restrict__ olo){
  __shared__ float TA[64][65];   // d 0..63   (K then V)
  __shared__ float TB[64][65];   // d 64..127
  __shared__ float qsh[16][128];
  int bid = blockIdx.x;
  int qb = bid & 63, h = (bid >> 6) & 15, b = bid >> 10;
  int q0 = qb * 16, kvh = h >> 1;
  int tid = threadIdx.x, wv = tid >> 6, ln = tid & 63;
  {
    int r = tid >> 4, d0 = (tid & 15) * 8;
    const float* src = xq + ((size_t)((b * 1024 + q0 + r) * 16 + h)) * 128 + d0;
    const float sc = 0.08838834764831845f;  // 1/sqrt(128)
    #pragma unroll
    for (int j = 0; j < 8; j++) qsh[r][d0 + j] = src[j] * sc;
  }
  float mr[4] = {-1e30f, -1e30f, -1e30f, -1e30f};
  float lr[4] = {0, 0, 0, 0}, o0[4] = {0, 0, 0, 0}, o1[4] = {0, 0, 0, 0};
  int r0 = wv * 4;
  int ntiles = q0 / 64 + 1;
  for (int t = 0; t < ntiles; t++){
    __syncthreads();
    {
      int j = tid >> 2, dc = (tid & 3) * 16;
      const float* ks = xk + ((size_t)((b * 1024 + t * 64 + j) * 8 + kvh)) * 128 + dc;
      #pragma unroll
      for (int i = 0; i < 16; i++){ TA[j][dc + i] = ks[i]; TB[j][dc + i] = ks[64 + i]; }
    }
    __syncthreads();
    float s0 = 0, s1 = 0, s2 = 0, s3 = 0;
    for (int d = 0; d < 64; d++){
      float kv = TA[ln][d];
      s0 = fmaf(qsh[r0][d], kv, s0);     s1 = fmaf(qsh[r0 + 1][d], kv, s1);
      s2 = fmaf(qsh[r0 + 2][d], kv, s2); s3 = fmaf(qsh[r0 + 3][d], kv, s3);
    }
    for (int d = 0; d < 64; d++){
      float kv = TB[ln][d];
      s0 = fmaf(qsh[r0][d + 64], kv, s0);     s1 = fmaf(qsh[r0 + 1][d + 64], kv, s1);
      s2 = fmaf(qsh[r0 + 2][d + 64], kv, s2); s3 = fmaf(qsh[r0 + 3][d + 64], kv, s3);
    }
    int key = t * 64 + ln;
    float sv[4] = {s0, s1, s2, s3};
    float pv4[4];
    #pragma unroll
    for (int rr = 0; rr < 4; rr++){
      int q = q0 + r0 + rr;
      float s = (key <= q) ? sv[rr] : -1e30f;
      float mt = s;
      #pragma unroll
      for (int of = 32; of; of >>= 1) mt = fmaxf(mt, __shfl_xor(mt, of));
      float mnew = fmaxf(mr[rr], mt);
      float p = __expf(s - mnew);
      float alpha = __expf(mr[rr] - mnew);
      float ps = p;
      #pragma unroll
      for (int of = 32; of; of >>= 1) ps += __shfl_xor(ps, of);
      lr[rr] = lr[rr] * alpha + ps; mr[rr] = mnew;
      o0[rr] *= alpha; o1[rr] *= alpha;
      pv4[rr] = p;
    }
    __syncthreads();
    {
      int j = tid >> 2, dc = (tid & 3) * 16;
      const float* vs = xv + ((size_t)((b * 1024 + t * 64 + j) * 8 + kvh)) * 128 + dc;
      #pragma unroll
      for (int i = 0; i < 16; i++){ TA[j][dc + i] = vs[i]; TB[j][dc + i] = vs[64 + i]; }
    }
    __syncthreads();
    for (int j = 0; j < 64; j++){
      float va = TA[j][ln], vb = TB[j][ln];
      float p0 = __shfl(pv4[0], j), p1 = __shfl(pv4[1], j);
      float p2 = __shfl(pv4[2], j), p3 = __shfl(pv4[3], j);
      o0[0] = fmaf(p0, va, o0[0]); o1[0] = fmaf(p0, vb, o1[0]);
      o0[1] = fmaf(p1, va, o0[1]); o1[1] = fmaf(p1, vb, o1[1]);
      o0[2] = fmaf(p2, va, o0[2]); o1[2] = fmaf(p2, vb, o1[2]);
      o0[3] = fmaf(p3, va, o0[3]); o1[3] = fmaf(p3, vb, o1[3]);
    }
  }
  #pragma unroll
  for (int rr = 0; rr < 4; rr++){
    int q = q0 + r0 + rr;
    float inv = 1.0f / lr[rr];
    size_t ob = ((size_t)(b * 1024 + q)) * 2048 + (size_t)h * 128;
    float v0 = o0[rr] * inv, v1 = o1[rr] * inv;
    bf16 h0 = __float2bfloat16(v0), h1 = __float2bfloat16(v1);
    ohi[ob + ln] = h0;      olo[ob + ln]      = __float2bfloat16(v0 - __bfloat162float(h0));
    ohi[ob + ln + 64] = h1; olo[ob + ln + 64] = __float2bfloat16(v1 - __bfloat162float(h1));
  }
}

// ---------------- small elementwise kernels ----------------
__global__ void resid_k(const int* __restrict__ flagp, const void* __restrict__ data,
                        const float* __restrict__ proj, float* __restrict__ d2, int n){
  int isf = flagp[0];
  int i = blockIdx.x * 256 + threadIdx.x;
  if (i >= n) return;
  d2[i] = ldin(data, i, isf) + proj[i];
}

__global__ void final_k(const int* __restrict__ flagp, const float* __restrict__ d2,
                        const float* __restrict__ moe, void* __restrict__ out, int n){
  int isf = flagp[0];
  int i = blockIdx.x * 256 + threadIdx.x;
  if (i >= n) return;
  float v = d2[i] + moe[i];
  if (isf) ((float*)out)[i] = v;
  else ((bf16*)out)[i] = __float2bfloat16(v);
}

// ---------------- packed per-pair SwiGLU with LoRA deltas ----------------
__global__ __launch_bounds__(256) void sr_pack(
    const int* __restrict__ flagp,
    const bf16* __restrict__ cw1, const bf16* __restrict__ cw3,
    const float* __restrict__ t1, const float* __restrict__ t3,
    const void* __restrict__ b1, const void* __restrict__ b3,
    int r0, const int* __restrict__ pidx, const int* __restrict__ pexp,
    bf16* __restrict__ srp)
{
  int isf = flagp[0];
  int p = blockIdx.y;
  int col0 = blockIdx.x * 256;
  int tid = threadIdx.x;
  int row = pidx[p];
  int e = pexp[p];
  int s = row - r0;
  __shared__ float sb1[16][256], sb3[16][256];
  __shared__ float st1[16], st3[16];
  for (int idx = tid; idx < 16 * 256; idx += 256){
    int r = idx >> 8; int c = idx & 255;
    sb1[r][c] = ldin(b1, ((size_t)e * 16 + r) * DFF + col0 + c, isf);
    sb3[r][c] = ldin(b3, ((size_t)e * 16 + r) * DFF + col0 + c, isf);
  }
  if (tid < 16){
    st1[tid] = t1[(size_t)row * 128 + e * 16 + tid];
    st3[tid] = t3[(size_t)row * 128 + e * 16 + tid];
  }
  __syncthreads();
  int j = col0 + tid;
  float x1 = __bfloat162float(cw1[(size_t)s * DFF + j]);
  float x3 = __bfloat162float(cw3[(size_t)s * DFF + j]);
  float l1 = 0.f, l3 = 0.f;
  #pragma unroll
  for (int r = 0; r < 16; r++){
    l1 = fmaf(st1[r], sb1[r][tid], l1);
    l3 = fmaf(st3[r], sb3[r][tid], l3);
  }
  x1 += 2.0f * l1; x3 += 2.0f * l3;
  float sig = 1.0f / (1.0f + __expf(-x1));
  srp[(size_t)p * DFF + j] = __float2bfloat16(x1 * sig * x3);
}

// ---------------- host ----------------
extern "C" void kernel_launch(void* const* d_in, const int* in_sizes, int n_in,
                              void* d_out, int out_size, void* d_ws, size_t ws_size,
                              hipStream_t stream) {
  (void)in_sizes; (void)n_in;
  const void* data   = d_in[0];
  const void* cosb   = d_in[2];
  const void* sinb   = d_in[3];
  const void* attn_w = d_in[4];
  const void* ffn_w  = d_in[5];
  const void* wq = d_in[6];
  const void* wk = d_in[7];
  const void* wvw = d_in[8];
  const void* wo = d_in[9];
  const void* qa = d_in[10];
  const void* qb = d_in[11];
  const void* ka = d_in[12];
  const void* kb = d_in[13];
  const void* va = d_in[14];
  const void* vb = d_in[15];
  const void* oa = d_in[16];
  const void* ob = d_in[17];
  const void* gate_w = d_in[18];
  const void* w1 = d_in[19];
  const void* w2 = d_in[20];
  const void* w3 = d_in[21];
  const void* a1 = d_in[22];
  const void* b1 = d_in[23];
  const void* a3 = d_in[24];
  const void* b3 = d_in[25];
  const void* a2 = d_in[26];
  const void* b2 = d_in[27];

  const int nElem = NT * DMODEL;
  dim3 blk(256);

  size_t need = ((size_t)81 << 20);
  if (ws_size < need){
    fill_b<<<(out_size + 255) / 256, blk, 0, stream>>>((bf16*)d_out,
        1000.0f + (float)(ws_size >> 20), out_size);
    return;
  }
  char* base = (char*)d_ws;
  float* data2 = (float*)(base);                       // [0,16) MB, persists
  float* accb  = (float*)(base + ((size_t)16 << 20));  // [16,32): attn proj -> moe acc
  bf16*  h_hi  = (bf16*)(base + ((size_t)32 << 20));   // [32,40): h hi -> o hi -> sn
  bf16*  h_lo  = (bf16*)(base + ((size_t)40 << 20));   // [40,48): h lo -> phase-B smalls
  float* xq = (float*)(base + ((size_t)48 << 20));     // [48,64)
  float* xk = (float*)(base + ((size_t)64 << 20));     // [64,72)
  float* xv = (float*)(base + ((size_t)72 << 20));     // [72,80)
  int*   flag = (int*)(base + ((size_t)80 << 20));     // [80,80+4)
  // tq..to2 live in data2's last 1 MB (data2 written only after their last use)
  float* tq  = (float*)(base + ((size_t)15 << 20));
  float* tk  = tq + (size_t)NT * 16;
  float* tv  = tk + (size_t)NT * 16;
  float* to2 = tv + (size_t)NT * 16;
  // phase-B smalls in h_lo region
  float* t1 = (float*)(base + ((size_t)40 << 20));     // NT*128 f32 = 1 MB
  float* t3 = t1 + (size_t)NT * 128;                   // 1 MB
  float* logits = t3 + (size_t)NT * 128;               // 64 KB
  float* ew = logits + NT * 8;                         // 64 KB
  float* t2p = ew + NT * 8;                            // NPAIR*16 f32 = 64 KB
  float* wgt = t2p + (size_t)NPAIR * 16;               // 4 KB
  int* pidx = (int*)(wgt + NPAIR);                     // 4 KB
  int* pexp = pidx + NPAIR;                            // 4 KB
  int* offp = pexp + NPAIR;                            // 36 B
  // phase-B big (reuse xq/xk/xv region, 32 MB)
  bf16* cw1h = (bf16*)(base + ((size_t)48 << 20));     // NH*DFF bf16 = 8 MB
  bf16* cw3h = (bf16*)(base + ((size_t)56 << 20));     // 8 MB
  bf16* srp  = (bf16*)(base + ((size_t)64 << 20));     // NPAIR*DFF bf16 = 16 MB
  bf16* sn = h_hi;

  detect_k<<<1, 64, 0, stream>>>(cosb, flag);

  // ---- attention block (fidelity via hi/lo split) ----
  rmsnorm_split<<<NT, blk, 0, stream>>>(flag, data, attn_w, h_hi, h_lo);
  zero_f<<<(NT * 16 * 4 + 255) / 256, blk, 0, stream>>>(tq, NT * 16 * 4);  // tq,tk,tv,to2
  gemm128_t<1><<<dim3(16,1,8), blk, 0, stream>>>(flag, h_hi, h_lo, 2048, qa, 0, 16, 16,
      tq, nullptr, 16, NT, 16, 2048, nullptr, 0, nullptr, 0, 0, nullptr, 0, 3);
  gemm128_t<1><<<dim3(16,1,8), blk, 0, stream>>>(flag, h_hi, h_lo, 2048, ka, 0, 16, 16,
      tk, nullptr, 16, NT, 16, 2048, nullptr, 0, nullptr, 0, 0, nullptr, 0, 3);
  gemm128_t<1><<<dim3(16,1,8), blk, 0, stream>>>(flag, h_hi, h_lo, 2048, va, 0, 16, 16,
      tv, nullptr, 16, NT, 16, 2048, nullptr, 0, nullptr, 0, 0, nullptr, 0, 3);
  gemm128_t<1><<<dim3(16,16,1), blk, 0, stream>>>(flag, h_hi, h_lo, 2048, wq, 0, 2048, 16,
      xq, nullptr, 2048, NT, 2048, 2048, tq, 16, qb, 0, 2048, nullptr, 0, 1);
  gemm128_t<1><<<dim3(16,8,1), blk, 0, stream>>>(flag, h_hi, h_lo, 2048, wk, 0, 1024, 16,
      xk, nullptr, 1024, NT, 1024, 2048, tk, 16, kb, 0, 1024, nullptr, 0, 1);
  gemm128_t<1><<<dim3(16,8,1), blk, 0, stream>>>(flag, h_hi, h_lo, 2048, wvw, 0, 1024, 16,
      xv, nullptr, 1024, NT, 1024, 2048, tv, 16, vb, 0, 1024, nullptr, 0, 1);
  rope_f32<<<8192, blk, 0, stream>>>(flag, xq, cosb, sinb, 16);
  rope_f32<<<4096, blk, 0, stream>>>(flag, xk, cosb, sinb, 8);
  flash_attn<<<2048, blk, 0, stream>>>(xq, xk, xv, h_hi, h_lo);   // o -> h_hi/h_lo
  zero_f<<<(NT * 16 + 255) / 256, blk, 0, stream>>>(to2, NT * 16);
  gemm128_t<1><<<dim3(16,1,8), blk, 0, stream>>>(flag, h_hi, h_lo, 2048, oa, 0, 16, 16,
      to2, nullptr, 16, NT, 16, 2048, nullptr, 0, nullptr, 0, 0, nullptr, 0, 3);
  gemm128_t<1><<<dim3(16,16,1), blk, 0, stream>>>(flag, h_hi, h_lo, 2048, wo, 0, 2048, 16,
      accb, nullptr, 2048, NT, 2048, 2048, to2, 16, ob, 0, 2048, nullptr, 0, 1);
  resid_k<<<(nElem + 255) / 256, blk, 0, stream>>>(flag, data, accb, data2, nElem);

  // ---- MoE prep ----
  rmsnorm_f32<<<NT, blk, 0, stream>>>(flag, data2, ffn_w, sn);
  logits_k<<<NT, blk, 0, stream>>>(flag, data2, ffn_w, gate_w, logits);
  route_ew<<<8, blk, 0, stream>>>(logits, ew);
  zero_f<<<(nElem + 255) / 256, blk, 0, stream>>>(accb, nElem);
  zero_f<<<(NT * 128 * 2 + 255) / 256, blk, 0, stream>>>(t1, NT * 128 * 2);   // t1,t3
  // all-expert LoRA t-projections (a1/a3 are [E][D][16]); split-K accumulate
  gemm128_t<0><<<dim3(16,1,8), blk, 0, stream>>>(flag, sn, nullptr, 2048, a1, 0, 16, 2048LL*16,
      t1, nullptr, 128, NT, 128, 2048, nullptr, 0, nullptr, 0, 0, nullptr, 0, 3);
  gemm128_t<0><<<dim3(16,1,8), blk, 0, stream>>>(flag, sn, nullptr, 2048, a3, 0, 16, 2048LL*16,
      t3, nullptr, 128, NT, 128, 2048, nullptr, 0, nullptr, 0, 0, nullptr, 0, 3);

  // ---- sparse MoE in 4 quarters of NH=512 rows, exactly NPAIR pairs each ----
  for (int hf = 0; hf < 4; hf++){
    int r0 = hf * NH;
    build_k<<<1, 512, 0, stream>>>(ew, r0, pidx, pexp, wgt, offp);
    gemm128_t<0><<<dim3(4,64,1), blk, 0, stream>>>(flag, sn + (size_t)r0 * 2048, nullptr, 2048,
        w1, 0, 8192, 16, nullptr, cw1h, 8192, NH, 8192, 2048,
        nullptr, 0, nullptr, 0, 0, nullptr, 0, 0);
    gemm128_t<0><<<dim3(4,64,1), blk, 0, stream>>>(flag, sn + (size_t)r0 * 2048, nullptr, 2048,
        w3, 0, 8192, 16, nullptr, cw3h, 8192, NH, 8192, 2048,
        nullptr, 0, nullptr, 0, 0, nullptr, 0, 0);
    sr_pack<<<dim3(32, NPAIR), blk, 0, stream>>>(flag, cw1h, cw3h, t1, t3, b1, b3,
        r0, pidx, pexp, srp);
    t2_pack<<<NPAIR, blk, 0, stream>>>(flag, srp, a2, pexp, t2p);
    gemm_w2<<<dim3(4,16,8), blk, 0, stream>>>(flag, srp, w2, b2, t2p, pidx, wgt, offp,
        accb);
  }
  final_k<<<(nElem + 255) / 256, blk, 0, stream>>>(flag, data2, accb, d_out, nElem);
}

// Round 5
// 5830.474 us; speedup vs baseline: 4.0001x; 1.7163x over previous
//
#include <hip/hip_runtime.h>
#include <hip/hip_bf16.h>
#include <cstdint>

// MixTransformer: B=2,S=1024,D=2048,H=16,KVH=8,HD=128,DFF=8192,E=8,K=2,R=16
// Round 9: fix gemm_w2 write-storm (R8: 2.4 GB WRITE_SIZE, 1420us, atomics).
// Key insight: w2 is SHARED across experts -> no expert segmentation needed.
// Pairs at fixed slots (row s -> 2s, 2s+1); gemm_w2 plain-stores to packed
// hsp (no atomics); gather_k sums the 2 pairs per token into accb (no zero_f).
// build_k deleted; route_pairs emits pexp/wgt directly.

typedef __hip_bfloat16 bf16;
typedef unsigned short u16;
typedef unsigned int u32;
typedef __attribute__((ext_vector_type(8))) short short8;
typedef __attribute__((ext_vector_type(4))) float floatx4;

#define NT 2048      // B*S
#define DMODEL 2048
#define DFF 8192
#define NH 512       // rows per MoE quarter-batch
#define NPAIR 1024   // NH * K(=2) pairs per quarter

__device__ __forceinline__ float ldin(const void* p, size_t i, int isf){
  return isf ? ((const float*)p)[i] : __bfloat162float(((const bf16*)p)[i]);
}
__device__ __forceinline__ u16 f2bu(float v){ bf16 h = __float2bfloat16(v); return *(u16*)&h; }
__device__ __forceinline__ float bu2f(u16 v){ u32 x = ((u32)v) << 16; return __uint_as_float(x); }
__device__ __forceinline__ u32 pk2(u16 a, u16 b){ return (u32)a | ((u32)b << 16); }

// ---------------- dtype detection: cos[0] == 1.0f ----------------
__global__ void detect_k(const void* __restrict__ cosp, int* __restrict__ flag){
  if (threadIdx.x == 0 && blockIdx.x == 0){
    u32 w = *(const u32*)cosp;
    flag[0] = (w == 0x3F800000u) ? 1 : 0;   // 1 = float32 inputs, 0 = bf16
  }
}

// ---------------- RMSNorm producing hi/lo bf16 split ----------------
__global__ __launch_bounds__(256) void rmsnorm_split(const int* __restrict__ flagp,
                                                     const void* __restrict__ x, const void* __restrict__ w,
                                                     bf16* __restrict__ hi, bf16* __restrict__ lo){
  int isf = flagp[0];
  int row = blockIdx.x; int tid = threadIdx.x;
  float ss = 0.f;
  for (int d = tid; d < DMODEL; d += 256){ float v = ldin(x, (size_t)row * DMODEL + d, isf); ss = fmaf(v, v, ss); }
  __shared__ float red[256];
  red[tid] = ss; __syncthreads();
  for (int s = 128; s > 0; s >>= 1){ if (tid < s) red[tid] += red[tid + s]; __syncthreads(); }
  float m = red[0] / (float)DMODEL + 1e-5f;
  float r = rsqrtf(m); r = r * (1.5f - 0.5f * m * r * r);  // Newton refine
  for (int d = tid; d < DMODEL; d += 256){
    float v = ldin(x, (size_t)row * DMODEL + d, isf) * r * ldin(w, d, isf);
    bf16 vh = __float2bfloat16(v);
    hi[(size_t)row * DMODEL + d] = vh;
    lo[(size_t)row * DMODEL + d] = __float2bfloat16(v - __bfloat162float(vh));
  }
}

// ---------------- RMSNorm f32 -> bf16 ----------------
__global__ __launch_bounds__(256) void rmsnorm_f32(const int* __restrict__ flagp,
                                                   const float* __restrict__ x, const void* __restrict__ w,
                                                   bf16* __restrict__ out){
  int isf = flagp[0];
  int row = blockIdx.x; int tid = threadIdx.x;
  const float* xr = x + (size_t)row * DMODEL;
  float ss = 0.f;
  for (int d = tid; d < DMODEL; d += 256){ float v = xr[d]; ss = fmaf(v, v, ss); }
  __shared__ float red[256];
  red[tid] = ss; __syncthreads();
  for (int s = 128; s > 0; s >>= 1){ if (tid < s) red[tid] += red[tid + s]; __syncthreads(); }
  float m = red[0] / (float)DMODEL + 1e-5f;
  float r = rsqrtf(m); r = r * (1.5f - 0.5f * m * r * r);
  for (int d = tid; d < DMODEL; d += 256)
    out[(size_t)row * DMODEL + d] = __float2bfloat16(xr[d] * r * ldin(w, d, isf));
}

// ---------------- Gate logits in f64 (routing precision) ----------------
__global__ __launch_bounds__(256) void logits_k(const int* __restrict__ flagp,
                                                const float* __restrict__ x, const void* __restrict__ w,
                                                const void* __restrict__ gw, float* __restrict__ out){
  int isf = flagp[0];
  int row = blockIdx.x; int tid = threadIdx.x;
  const float* xr = x + (size_t)row * DMODEL;
  __shared__ double red[256];
  double ss = 0.0;
  for (int d = tid; d < DMODEL; d += 256){ double v = xr[d]; ss += v * v; }
  red[tid] = ss; __syncthreads();
  for (int s = 128; s > 0; s >>= 1){ if (tid < s) red[tid] += red[tid + s]; __syncthreads(); }
  double scale = 1.0 / sqrt(red[0] / (double)DMODEL + 1e-5);
  double acc[8] = {0,0,0,0,0,0,0,0};
  for (int d = tid; d < DMODEL; d += 256){
    double sv = (double)xr[d] * scale * (double)ldin(w, d, isf);
    #pragma unroll
    for (int e = 0; e < 8; e++) acc[e] += sv * (double)ldin(gw, (size_t)d * 8 + e, isf);
  }
  __shared__ double red8[256][8];
  #pragma unroll
  for (int e = 0; e < 8; e++) red8[tid][e] = acc[e];
  __syncthreads();
  for (int s = 128; s > 0; s >>= 1){
    if (tid < s){ for (int e = 0; e < 8; e++) red8[tid][e] += red8[tid + s][e]; }
    __syncthreads();
  }
  if (tid < 8) out[row * 8 + tid] = (float)red8[0][tid];
}

// ---------------- Routing -> per-row pair slots (2s, 2s+1) ----------------
__global__ void route_pairs(const float* __restrict__ logits,
                            int* __restrict__ pexp, float* __restrict__ wgt){
  int row = blockIdx.x * 256 + threadIdx.x;
  if (row >= NT) return;
  float l[8]; float mx = -1e30f;
  for (int e = 0; e < 8; e++){ l[e] = logits[row * 8 + e]; mx = fmaxf(mx, l[e]); }
  float p[8];
  for (int e = 0; e < 8; e++) p[e] = expf(l[e] - mx);
  int e1 = 0; float b1v = p[0];
  for (int e = 1; e < 8; e++) if (p[e] > b1v){ b1v = p[e]; e1 = e; }
  int e2 = 0; float b2v = -1.f;
  for (int e = 0; e < 8; e++) if (e != e1 && p[e] > b2v){ b2v = p[e]; e2 = e; }
  float s = b1v + b2v;
  pexp[2 * row]     = e1; wgt[2 * row]     = b1v / s;
  pexp[2 * row + 1] = e2; wgt[2 * row + 1] = b2v / s;
}

__global__ void zero_f(float* __restrict__ p, int n){
  int i = blockIdx.x * 256 + threadIdx.x;
  if (i < n) p[i] = 0.f;
}
__global__ void fill_b(bf16* __restrict__ p, float v, int n){
  int i = blockIdx.x * 256 + threadIdx.x;
  if (i < n) p[i] = __float2bfloat16(v);
}

// ---------------- 128x128-tile MFMA GEMM ----------------
// C = A@W (+fidelity passes) (+ 2*lt@lB LoRA epilogue)
// A,A2: bf16 [M][lda] (A2 = lo split when FID). W: f32 or bf16 by flag.
// W element (k,n) at: wOff + k*ldw + (n>>4)*wstride + (n&15)   (wstride=16 -> plain)
// FID: acc += Ahi*Whi + Alo*Whi (+ Ahi*Wlo when W is f32).
// mode 0: Cb=bf16(c); 1: Cf=c; 3: atomicAdd(Cf, c) [split-K; caller zero-inits]
// Split-K via gridDim.z; LoRA applied only on z==0 chunk.
// Requires M%128==0, Kd%(32*gridDim.z)==0. N guarded (OOB cols stage zeros).
template<int FID>
__global__ __launch_bounds__(256) void gemm128_t(
    const int* __restrict__ flagp,
    const bf16* __restrict__ A, const bf16* __restrict__ A2, int lda,
    const void* __restrict__ W, long long wOff, int ldw, long long wstride,
    float* __restrict__ Cf, bf16* __restrict__ Cb, int ldc,
    int M, int N, int Kd,
    const float* __restrict__ lt, int ldt,
    const void* __restrict__ lB, long long lbOff, int ldlB,
    int mode)
{
  int isf = flagp[0];
  int m0 = blockIdx.x * 128;
  int n0 = blockIdx.y * 128;
  if (m0 >= M) return;
  int nz = gridDim.z;
  int ksteps = (Kd >> 5) / nz;
  int k0beg = blockIdx.z * ksteps * 32;

  __shared__ __align__(16) u16 Ah[128][32];                 // 8 KB, linear 64B rows
  __shared__ __align__(16) u16 Bh[128][40];                 // 10 KB, [n][k], pad->aligned b128
  __shared__ __align__(16) u16 Al[FID ? 128 : 1][32];
  __shared__ __align__(16) u16 Bl[FID ? 128 : 1][40];

  int tid = threadIdx.x;
  int wv = tid >> 6, ln = tid & 63;
  int wr = wv >> 1, wc = wv & 1;

  // A staging: rows s_ar, s_ar+64; 8-elem chunk s_ac (coalesced: 4 lanes = 64B row)
  int s_ar = tid >> 2;
  int s_ac = (tid & 3) * 8;
  const bf16* Ap0 = A + (size_t)(m0 + s_ar) * lda + s_ac;
  const bf16* Ap1 = A + (size_t)(m0 + s_ar + 64) * lda + s_ac;
  const bf16* Ap0l = Ap0; const bf16* Ap1l = Ap1;
  if (FID){ Ap0l = A2 + (size_t)(m0 + s_ar) * lda + s_ac; Ap1l = A2 + (size_t)(m0 + s_ar + 64) * lda + s_ac; }

  // B staging: col pair (s_bn, s_bn+1), k-octet s_bk
  int s_bn = (tid & 63) * 2;
  int s_bk = (tid >> 6) * 8;
  int gn0 = n0 + s_bn;
  bool bval = gn0 < N;
  long long colOff0 = wOff + (long long)(gn0 >> 4) * wstride + (gn0 & 15);
  const float* Wf = (const float*)W;
  const bf16*  Wb = (const bf16*)W;

  floatx4 acc[4][4];
  #pragma unroll
  for (int a = 0; a < 4; a++)
    #pragma unroll
    for (int b = 0; b < 4; b++) acc[a][b] = (floatx4){0.f, 0.f, 0.f, 0.f};

  uint4 pa0 = {0,0,0,0}, pa1 = {0,0,0,0}, pl0 = {0,0,0,0}, pl1 = {0,0,0,0};
  float pbf[16];
  u32 pbb[8];
  #pragma unroll
  for (int i = 0; i < 16; i++) pbf[i] = 0.f;
  #pragma unroll
  for (int i = 0; i < 8; i++) pbb[i] = 0;

  // prefetch first K-tile
  pa0 = *(const uint4*)(Ap0 + k0beg);
  pa1 = *(const uint4*)(Ap1 + k0beg);
  if (FID){ pl0 = *(const uint4*)(Ap0l + k0beg); pl1 = *(const uint4*)(Ap1l + k0beg); }
  if (bval){
    if (isf){
      #pragma unroll
      for (int i = 0; i < 8; i++){
        float2 v = *(const float2*)(Wf + ((long long)(k0beg + s_bk + i) * ldw + colOff0));
        pbf[i] = v.x; pbf[8 + i] = v.y;
      }
    } else {
      #pragma unroll
      for (int i = 0; i < 8; i++)
        pbb[i] = *(const u32*)(Wb + ((long long)(k0beg + s_bk + i) * ldw + colOff0));
    }
  }

  for (int ks = 0; ks < ksteps; ks++){
    __syncthreads();    // previous iteration's fragment reads complete
    // ---- commit staged tile to LDS ----
    *(uint4*)&Ah[s_ar][s_ac] = pa0;
    *(uint4*)&Ah[s_ar + 64][s_ac] = pa1;
    if (FID){
      *(uint4*)&Al[s_ar][s_ac] = pl0;
      *(uint4*)&Al[s_ar + 64][s_ac] = pl1;
    }
    {
      u16 h[16], l[16];
      if (bval && isf){
        #pragma unroll
        for (int i = 0; i < 16; i++){ h[i] = f2bu(pbf[i]); l[i] = f2bu(pbf[i] - bu2f(h[i])); }
      } else if (bval){
        #pragma unroll
        for (int i = 0; i < 8; i++){ h[i] = (u16)(pbb[i] & 0xffff); h[8 + i] = (u16)(pbb[i] >> 16); l[i] = 0; l[8 + i] = 0; }
      } else {
        #pragma unroll
        for (int i = 0; i < 16; i++){ h[i] = 0; l[i] = 0; }
      }
      uint4 H0, H1;
      H0.x = pk2(h[0], h[1]);  H0.y = pk2(h[2], h[3]);  H0.z = pk2(h[4], h[5]);  H0.w = pk2(h[6], h[7]);
      H1.x = pk2(h[8], h[9]);  H1.y = pk2(h[10], h[11]); H1.z = pk2(h[12], h[13]); H1.w = pk2(h[14], h[15]);
      *(uint4*)&Bh[s_bn][s_bk]     = H0;
      *(uint4*)&Bh[s_bn + 1][s_bk] = H1;
      if (FID && isf){
        uint4 L0, L1;
        L0.x = pk2(l[0], l[1]);  L0.y = pk2(l[2], l[3]);  L0.z = pk2(l[4], l[5]);  L0.w = pk2(l[6], l[7]);
        L1.x = pk2(l[8], l[9]);  L1.y = pk2(l[10], l[11]); L1.z = pk2(l[12], l[13]); L1.w = pk2(l[14], l[15]);
        *(uint4*)&Bl[s_bn][s_bk]     = L0;
        *(uint4*)&Bl[s_bn + 1][s_bk] = L1;
      }
    }
    // ---- issue next K-tile loads (latency hides under MFMA phase) ----
    if (ks + 1 < ksteps){
      int kn = k0beg + (ks + 1) * 32;
      pa0 = *(const uint4*)(Ap0 + kn);
      pa1 = *(const uint4*)(Ap1 + kn);
      if (FID){ pl0 = *(const uint4*)(Ap0l + kn); pl1 = *(const uint4*)(Ap1l + kn); }
      if (bval){
        if (isf){
          #pragma unroll
          for (int i = 0; i < 8; i++){
            float2 v = *(const float2*)(Wf + ((long long)(kn + s_bk + i) * ldw + colOff0));
            pbf[i] = v.x; pbf[8 + i] = v.y;
          }
        } else {
          #pragma unroll
          for (int i = 0; i < 8; i++)
            pbb[i] = *(const u32*)(Wb + ((long long)(kn + s_bk + i) * ldw + colOff0));
        }
      }
    }
    __syncthreads();    // staging visible
    // ---- MFMA phase ----
    short8 ah[4], al4[4];
    #pragma unroll
    for (int mt = 0; mt < 4; mt++)
      ah[mt] = *(const short8*)&Ah[wr * 64 + mt * 16 + (ln & 15)][(ln >> 4) * 8];
    if (FID){
      #pragma unroll
      for (int mt = 0; mt < 4; mt++)
        al4[mt] = *(const short8*)&Al[wr * 64 + mt * 16 + (ln & 15)][(ln >> 4) * 8];
    }
    #pragma unroll
    for (int nt = 0; nt < 4; nt++){
      short8 bh = *(const short8*)&Bh[wc * 64 + nt * 16 + (ln & 15)][(ln >> 4) * 8];
      #pragma unroll
      for (int mt = 0; mt < 4; mt++)
        acc[mt][nt] = __builtin_amdgcn_mfma_f32_16x16x32_bf16(ah[mt], bh, acc[mt][nt], 0, 0, 0);
      if (FID){
        #pragma unroll
        for (int mt = 0; mt < 4; mt++)
          acc[mt][nt] = __builtin_amdgcn_mfma_f32_16x16x32_bf16(al4[mt], bh, acc[mt][nt], 0, 0, 0);
        if (isf){
          short8 bl = *(const short8*)&Bl[wc * 64 + nt * 16 + (ln & 15)][(ln >> 4) * 8];
          #pragma unroll
          for (int mt = 0; mt < 4; mt++)
            acc[mt][nt] = __builtin_amdgcn_mfma_f32_16x16x32_bf16(ah[mt], bl, acc[mt][nt], 0, 0, 0);
        }
      }
    }
  }

  // ---- epilogue ----
  int rl = (ln >> 4) * 4;
  int cl = ln & 15;
  bool doL = (lt != nullptr) && (blockIdx.z == 0);
  #pragma unroll
  for (int nt = 0; nt < 4; nt++){
    int gn = n0 + wc * 64 + nt * 16 + cl;
    if (gn >= N) continue;
    #pragma unroll
    for (int mt = 0; mt < 4; mt++){
      int gmb = m0 + wr * 64 + mt * 16 + rl;
      #pragma unroll
      for (int i = 0; i < 4; i++){
        int gm = gmb + i;
        float c = acc[mt][nt][i];
        if (doL){
          const float* tr = lt + (size_t)gm * ldt;
          float l = 0.f;
          #pragma unroll
          for (int r = 0; r < 16; r++)
            l = fmaf(tr[r], ldin(lB, (size_t)(lbOff + (long long)r * ldlB + gn), isf), l);
          c += 2.0f * l;   // SCALING = 2.0
        }
        size_t ci = (size_t)gm * ldc + gn;
        if (mode == 0) Cb[ci] = __float2bfloat16(c);
        else if (mode == 1) Cf[ci] = c;
        else atomicAdd(&Cf[ci], c);          // mode 3
      }
    }
  }
}

// ---------------- packed-pair w2 GEMM (w2 SHARED across experts) -------------
// srp: [NPAIR][DFF] bf16 (slot p = 2s+j for row s). grid (8,16), all blocks full.
// Epilogue: c = acc + 2*t2p[p]@b2[pexp[p]]; hsp[p*2048+gn] = c * wgt[p]. No atomics.
__global__ __launch_bounds__(256) void gemm_w2(
    const int* __restrict__ flagp,
    const bf16* __restrict__ srp,
    const void* __restrict__ W,          // w2 [DFF][2048]
    const void* __restrict__ b2,         // [E][16][2048]
    const float* __restrict__ t2p,       // [NPAIR][16]
    const int* __restrict__ pexpq, const float* __restrict__ wgtq,
    float* __restrict__ hsp)             // [NPAIR][2048]
{
  int isf = flagp[0];
  int m0 = blockIdx.x * 128;
  int n0 = blockIdx.y * 128;

  __shared__ __align__(16) u16 Ah[128][32];
  __shared__ __align__(16) u16 Bh[128][40];

  int tid = threadIdx.x;
  int wv = tid >> 6, ln = tid & 63;
  int wr = wv >> 1, wc = wv & 1;

  int s_ar = tid >> 2;
  int s_ac = (tid & 3) * 8;
  const bf16* Ap0 = srp + (size_t)(m0 + s_ar) * DFF + s_ac;
  const bf16* Ap1 = srp + (size_t)(m0 + s_ar + 64) * DFF + s_ac;

  int s_bn = (tid & 63) * 2;
  int s_bk = (tid >> 6) * 8;
  int gn0 = n0 + s_bn;                  // < 2048 always
  const float* Wf = (const float*)W;
  const bf16*  Wb = (const bf16*)W;

  floatx4 acc[4][4];
  #pragma unroll
  for (int a = 0; a < 4; a++)
    #pragma unroll
    for (int b = 0; b < 4; b++) acc[a][b] = (floatx4){0.f, 0.f, 0.f, 0.f};

  uint4 pa0, pa1;
  float pbf[16];
  u32 pbb[8];

  pa0 = *(const uint4*)(Ap0);
  pa1 = *(const uint4*)(Ap1);
  if (isf){
    #pragma unroll
    for (int i = 0; i < 8; i++){
      float2 v = *(const float2*)(Wf + ((long long)(s_bk + i) * 2048 + gn0));
      pbf[i] = v.x; pbf[8 + i] = v.y;
    }
  } else {
    #pragma unroll
    for (int i = 0; i < 8; i++)
      pbb[i] = *(const u32*)(Wb + ((long long)(s_bk + i) * 2048 + gn0));
  }

  const int ksteps = DFF / 32;          // 256
  for (int ks = 0; ks < ksteps; ks++){
    __syncthreads();
    *(uint4*)&Ah[s_ar][s_ac] = pa0;
    *(uint4*)&Ah[s_ar + 64][s_ac] = pa1;
    {
      u16 h[16];
      if (isf){
        #pragma unroll
        for (int i = 0; i < 16; i++) h[i] = f2bu(pbf[i]);
      } else {
        #pragma unroll
        for (int i = 0; i < 8; i++){ h[i] = (u16)(pbb[i] & 0xffff); h[8 + i] = (u16)(pbb[i] >> 16); }
      }
      uint4 H0, H1;
      H0.x = pk2(h[0], h[1]);  H0.y = pk2(h[2], h[3]);  H0.z = pk2(h[4], h[5]);  H0.w = pk2(h[6], h[7]);
      H1.x = pk2(h[8], h[9]);  H1.y = pk2(h[10], h[11]); H1.z = pk2(h[12], h[13]); H1.w = pk2(h[14], h[15]);
      *(uint4*)&Bh[s_bn][s_bk]     = H0;
      *(uint4*)&Bh[s_bn + 1][s_bk] = H1;
    }
    if (ks + 1 < ksteps){
      int kn = (ks + 1) * 32;
      pa0 = *(const uint4*)(Ap0 + kn);
      pa1 = *(const uint4*)(Ap1 + kn);
      if (isf){
        #pragma unroll
        for (int i = 0; i < 8; i++){
          float2 v = *(const float2*)(Wf + ((long long)(kn + s_bk + i) * 2048 + gn0));
          pbf[i] = v.x; pbf[8 + i] = v.y;
        }
      } else {
        #pragma unroll
        for (int i = 0; i < 8; i++)
          pbb[i] = *(const u32*)(Wb + ((long long)(kn + s_bk + i) * 2048 + gn0));
      }
    }
    __syncthreads();
    short8 ah[4];
    #pragma unroll
    for (int mt = 0; mt < 4; mt++)
      ah[mt] = *(const short8*)&Ah[wr * 64 + mt * 16 + (ln & 15)][(ln >> 4) * 8];
    #pragma unroll
    for (int nt = 0; nt < 4; nt++){
      short8 bh = *(const short8*)&Bh[wc * 64 + nt * 16 + (ln & 15)][(ln >> 4) * 8];
      #pragma unroll
      for (int mt = 0; mt < 4; mt++)
        acc[mt][nt] = __builtin_amdgcn_mfma_f32_16x16x32_bf16(ah[mt], bh, acc[mt][nt], 0, 0, 0);
    }
  }

  // epilogue: per-row expert lookup, fused b2-LoRA, plain stores
  int rl = (ln >> 4) * 4;
  int cl = ln & 15;
  #pragma unroll
  for (int mt = 0; mt < 4; mt++){
    #pragma unroll
    for (int i = 0; i < 4; i++){
      int gm = m0 + wr * 64 + mt * 16 + rl + i;
      int e = pexpq[gm];
      float w = wgtq[gm];
      long long eOff = (long long)e * 16 * 2048;
      float tr[16];
      #pragma unroll
      for (int r = 0; r < 16; r++) tr[r] = t2p[(size_t)gm * 16 + r];
      #pragma unroll
      for (int nt = 0; nt < 4; nt++){
        int gn = n0 + wc * 64 + nt * 16 + cl;
        float l = 0.f;
        #pragma unroll
        for (int r = 0; r < 16; r++)
          l = fmaf(tr[r], ldin(b2, (size_t)(eOff + (long long)r * 2048 + gn), isf), l);
        hsp[(size_t)gm * 2048 + gn] = (acc[mt][nt][i] + 2.0f * l) * w;
      }
    }
  }
}

// ---------------- gather: accb[row] = hsp[2s] + hsp[2s+1] ----------------
__global__ void gather_k(const float* __restrict__ hsp, float* __restrict__ accb, int r0){
  int i = blockIdx.x * 256 + threadIdx.x;
  if (i >= NH * 2048) return;
  int s = i >> 11, gn = i & 2047;
  accb[(size_t)(r0 + s) * 2048 + gn] =
      hsp[(size_t)(2 * s) * 2048 + gn] + hsp[(size_t)(2 * s + 1) * 2048 + gn];
}

// ---------------- t2p = srp @ a2[pexp]  (per-pair reduction, [NPAIR][16]) ------
__global__ __launch_bounds__(256) void t2_pack(const int* __restrict__ flagp,
    const bf16* __restrict__ srp, const void* __restrict__ a2,
    const int* __restrict__ pexpq, float* __restrict__ t2p)
{
  int isf = flagp[0];
  int p = blockIdx.x;
  int tid = threadIdx.x;
  int wv = tid >> 6, ln = tid & 63;
  long long aOff = (long long)pexpq[p] * DFF * 16;
  const bf16* srow = srp + (size_t)p * DFF;
  float acc[16];
  #pragma unroll
  for (int r = 0; r < 16; r++) acc[r] = 0.f;
  for (int kb = tid * 8; kb < DFF; kb += 2048){
    short8 v8 = *(const short8*)(srow + kb);
    #pragma unroll
    for (int j = 0; j < 8; j++){
      float v = bu2f((u16)v8[j]);
      #pragma unroll
      for (int r = 0; r < 16; r++)
        acc[r] = fmaf(v, ldin(a2, (size_t)(aOff + (long long)(kb + j) * 16 + r), isf), acc[r]);
    }
  }
  __shared__ float part[4][16];
  #pragma unroll
  for (int r = 0; r < 16; r++){
    float v = acc[r];
    #pragma unroll
    for (int of = 32; of; of >>= 1) v += __shfl_xor(v, of);
    if (ln == 0) part[wv][r] = v;
  }
  __syncthreads();
  if (tid < 16) t2p[(size_t)p * 16 + tid] = part[0][tid] + part[1][tid] + part[2][tid] + part[3][tid];
}

// ---------------- RoPE (f32, in place) ----------------
__global__ void rope_f32(const int* __restrict__ flagp, float* __restrict__ x,
                         const void* __restrict__ cosb, const void* __restrict__ sinb, int nHd){
  int isf = flagp[0];
  int idx = blockIdx.x * 256 + threadIdx.x;
  int d = idx & 63; int t = idx >> 6;
  int hh = t % nHd; t /= nHd;
  int s = t & 1023; int b = t >> 10;
  if (b >= 2) return;
  float* p = x + (((size_t)(b * 1024 + s)) * nHd + hh) * 128;
  float x1 = p[d], x2 = p[d + 64];
  float c1 = ldin(cosb, (size_t)s * 128 + d, isf);
  float s1 = ldin(sinb, (size_t)s * 128 + d, isf);
  float c2 = ldin(cosb, (size_t)s * 128 + d + 64, isf);
  float s2 = ldin(sinb, (size_t)s * 128 + d + 64, isf);
  p[d]      = x1 * c1 - x2 * s1;
  p[d + 64] = x2 * c2 + x1 * s2;
}

// ---------------- Flash attention, f32, causal, GQA; writes split-bf16 output ----
__global__ __launch_bounds__(256) void flash_attn(const float* __restrict__ xq, const float* __restrict__ xk,
                                                  const float* __restrict__ xv,
                                                  bf16* __restrict__ ohi, bf16* __restrict__ olo){
  __shared__ float TA[64][65];   // d 0..63   (K then V)
  __shared__ float TB[64][65];   // d 64..127
  __shared__ float qsh[16][128];
  int bid = blockIdx.x;
  int qb = bid & 63, h = (bid >> 6) & 15, b = bid >> 10;
  int q0 = qb * 16, kvh = h >> 1;
  int tid = threadIdx.x, wv = tid >> 6, ln = tid & 63;
  {
    int r = tid >> 4, d0 = (tid & 15) * 8;
    const float* src = xq + ((size_t)((b * 1024 + q0 + r) * 16 + h)) * 128 + d0;
    const float sc = 0.08838834764831845f;  // 1/sqrt(128)
    #pragma unroll
    for (int j = 0; j < 8; j++) qsh[r][d0 + j] = src[j] * sc;
  }
  float mr[4] = {-1e30f, -1e30f, -1e30f, -1e30f};
  float lr[4] = {0, 0, 0, 0}, o0[4] = {0, 0, 0, 0}, o1[4] = {0, 0, 0, 0};
  int r0 = wv * 4;
  int ntiles = q0 / 64 + 1;
  for (int t = 0; t < ntiles; t++){
    __syncthreads();
    {
      int j = tid >> 2, dc = (tid & 3) * 16;
      const float* ks = xk + ((size_t)((b * 1024 + t * 64 + j) * 8 + kvh)) * 128 + dc;
      #pragma unroll
      for (int i = 0; i < 16; i++){ TA[j][dc + i] = ks[i]; TB[j][dc + i] = ks[64 + i]; }
    }
    __syncthreads();
    float s0 = 0, s1 = 0, s2 = 0, s3 = 0;
    for (int d = 0; d < 64; d++){
      float kv = TA[ln][d];
      s0 = fmaf(qsh[r0][d], kv, s0);     s1 = fmaf(qsh[r0 + 1][d], kv, s1);
      s2 = fmaf(qsh[r0 + 2][d], kv, s2); s3 = fmaf(qsh[r0 + 3][d], kv, s3);
    }
    for (int d = 0; d < 64; d++){
      float kv = TB[ln][d];
      s0 = fmaf(qsh[r0][d + 64], kv, s0);     s1 = fmaf(qsh[r0 + 1][d + 64], kv, s1);
      s2 = fmaf(qsh[r0 + 2][d + 64], kv, s2); s3 = fmaf(qsh[r0 + 3][d + 64], kv, s3);
    }
    int key = t * 64 + ln;
    float sv[4] = {s0, s1, s2, s3};
    float pv4[4];
    #pragma unroll
    for (int rr = 0; rr < 4; rr++){
      int q = q0 + r0 + rr;
      float s = (key <= q) ? sv[rr] : -1e30f;
      float mt = s;
      #pragma unroll
      for (int of = 32; of; of >>= 1) mt = fmaxf(mt, __shfl_xor(mt, of));
      float mnew = fmaxf(mr[rr], mt);
      float p = __expf(s - mnew);
      float alpha = __expf(mr[rr] - mnew);
      float ps = p;
      #pragma unroll
      for (int of = 32; of; of >>= 1) ps += __shfl_xor(ps, of);
      lr[rr] = lr[rr] * alpha + ps; mr[rr] = mnew;
      o0[rr] *= alpha; o1[rr] *= alpha;
      pv4[rr] = p;
    }
    __syncthreads();
    {
      int j = tid >> 2, dc = (tid & 3) * 16;
      const float* vs = xv + ((size_t)((b * 1024 + t * 64 + j) * 8 + kvh)) * 128 + dc;
      #pragma unroll
      for (int i = 0; i < 16; i++){ TA[j][dc + i] = vs[i]; TB[j][dc + i] = vs[64 + i]; }
    }
    __syncthreads();
    for (int j = 0; j < 64; j++){
      float va = TA[j][ln], vb = TB[j][ln];
      float p0 = __shfl(pv4[0], j), p1 = __shfl(pv4[1], j);
      float p2 = __shfl(pv4[2], j), p3 = __shfl(pv4[3], j);
      o0[0] = fmaf(p0, va, o0[0]); o1[0] = fmaf(p0, vb, o1[0]);
      o0[1] = fmaf(p1, va, o0[1]); o1[1] = fmaf(p1, vb, o1[1]);
      o0[2] = fmaf(p2, va, o0[2]); o1[2] = fmaf(p2, vb, o1[2]);
      o0[3] = fmaf(p3, va, o0[3]); o1[3] = fmaf(p3, vb, o1[3]);
    }
  }
  #pragma unroll
  for (int rr = 0; rr < 4; rr++){
    int q = q0 + r0 + rr;
    float inv = 1.0f / lr[rr];
    size_t ob = ((size_t)(b * 1024 + q)) * 2048 + (size_t)h * 128;
    float v0 = o0[rr] * inv, v1 = o1[rr] * inv;
    bf16 h0 = __float2bfloat16(v0), h1 = __float2bfloat16(v1);
    ohi[ob + ln] = h0;      olo[ob + ln]      = __float2bfloat16(v0 - __bfloat162float(h0));
    ohi[ob + ln + 64] = h1; olo[ob + ln + 64] = __float2bfloat16(v1 - __bfloat162float(h1));
  }
}

// ---------------- small elementwise kernels ----------------
__global__ void resid_k(const int* __restrict__ flagp, const void* __restrict__ data,
                        const float* __restrict__ proj, float* __restrict__ d2, int n){
  int isf = flagp[0];
  int i = blockIdx.x * 256 + threadIdx.x;
  if (i >= n) return;
  d2[i] = ldin(data, i, isf) + proj[i];
}

__global__ void final_k(const int* __restrict__ flagp, const float* __restrict__ d2,
                        const float* __restrict__ moe, void* __restrict__ out, int n){
  int isf = flagp[0];
  int i = blockIdx.x * 256 + threadIdx.x;
  if (i >= n) return;
  float v = d2[i] + moe[i];
  if (isf) ((float*)out)[i] = v;
  else ((bf16*)out)[i] = __float2bfloat16(v);
}

// ---------------- packed per-pair SwiGLU with LoRA deltas ----------------
__global__ __launch_bounds__(256) void sr_pack(
    const int* __restrict__ flagp,
    const bf16* __restrict__ cw1, const bf16* __restrict__ cw3,
    const float* __restrict__ t1, const float* __restrict__ t3,
    const void* __restrict__ b1, const void* __restrict__ b3,
    int r0, const int* __restrict__ pexpq,
    bf16* __restrict__ srp)
{
  int isf = flagp[0];
  int p = blockIdx.y;
  int col0 = blockIdx.x * 256;
  int tid = threadIdx.x;
  int s = p >> 1;
  int row = r0 + s;
  int e = pexpq[p];
  __shared__ float sb1[16][256], sb3[16][256];
  __shared__ float st1[16], st3[16];
  for (int idx = tid; idx < 16 * 256; idx += 256){
    int r = idx >> 8; int c = idx & 255;
    sb1[r][c] = ldin(b1, ((size_t)e * 16 + r) * DFF + col0 + c, isf);
    sb3[r][c] = ldin(b3, ((size_t)e * 16 + r) * DFF + col0 + c, isf);
  }
  if (tid < 16){
    st1[tid] = t1[(size_t)row * 128 + e * 16 + tid];
    st3[tid] = t3[(size_t)row * 128 + e * 16 + tid];
  }
  __syncthreads();
  int j = col0 + tid;
  float x1 = __bfloat162float(cw1[(size_t)s * DFF + j]);
  float x3 = __bfloat162float(cw3[(size_t)s * DFF + j]);
  float l1 = 0.f, l3 = 0.f;
  #pragma unroll
  for (int r = 0; r < 16; r++){
    l1 = fmaf(st1[r], sb1[r][tid], l1);
    l3 = fmaf(st3[r], sb3[r][tid], l3);
  }
  x1 += 2.0f * l1; x3 += 2.0f * l3;
  float sig = 1.0f / (1.0f + __expf(-x1));
  srp[(size_t)p * DFF + j] = __float2bfloat16(x1 * sig * x3);
}

// ---------------- host ----------------
extern "C" void kernel_launch(void* const* d_in, const int* in_sizes, int n_in,
                              void* d_out, int out_size, void* d_ws, size_t ws_size,
                              hipStream_t stream) {
  (void)in_sizes; (void)n_in;
  const void* data   = d_in[0];
  const void* cosb   = d_in[2];
  const void* sinb   = d_in[3];
  const void* attn_w = d_in[4];
  const void* ffn_w  = d_in[5];
  const void* wq = d_in[6];
  const void* wk = d_in[7];
  const void* wvw = d_in[8];
  const void* wo = d_in[9];
  const void* qa = d_in[10];
  const void* qb = d_in[11];
  const void* ka = d_in[12];
  const void* kb = d_in[13];
  const void* va = d_in[14];
  const void* vb = d_in[15];
  const void* oa = d_in[16];
  const void* ob = d_in[17];
  const void* gate_w = d_in[18];
  const void* w1 = d_in[19];
  const void* w2 = d_in[20];
  const void* w3 = d_in[21];
  const void* a1 = d_in[22];
  const void* b1 = d_in[23];
  const void* a3 = d_in[24];
  const void* b3 = d_in[25];
  const void* a2 = d_in[26];
  const void* b2 = d_in[27];

  const int nElem = NT * DMODEL;
  dim3 blk(256);

  size_t need = ((size_t)81 << 20);
  if (ws_size < need){
    fill_b<<<(out_size + 255) / 256, blk, 0, stream>>>((bf16*)d_out,
        1000.0f + (float)(ws_size >> 20), out_size);
    return;
  }
  char* base = (char*)d_ws;
  float* data2 = (float*)(base);                       // [0,16) MB, persists
  float* accb  = (float*)(base + ((size_t)16 << 20));  // [16,32): attn proj -> moe out
  bf16*  h_hi  = (bf16*)(base + ((size_t)32 << 20));   // [32,40): h hi -> o hi -> sn
  bf16*  h_lo  = (bf16*)(base + ((size_t)40 << 20));   // [40,48): h lo -> phase-B smalls
  float* xq = (float*)(base + ((size_t)48 << 20));     // [48,64)
  float* xk = (float*)(base + ((size_t)64 << 20));     // [64,72)
  float* xv = (float*)(base + ((size_t)72 << 20));     // [72,80)
  int*   flag = (int*)(base + ((size_t)80 << 20));     // [80,80+4)
  // tq..to2 live in data2's last 1 MB (data2 written only after their last use)
  float* tq  = (float*)(base + ((size_t)15 << 20));
  float* tk  = tq + (size_t)NT * 16;
  float* tv  = tk + (size_t)NT * 16;
  float* to2 = tv + (size_t)NT * 16;
  // phase-B smalls in h_lo region
  float* t1 = (float*)(base + ((size_t)40 << 20));     // NT*128 f32 = 1 MB
  float* t3 = t1 + (size_t)NT * 128;                   // 1 MB
  float* logits = t3 + (size_t)NT * 128;               // 64 KB
  float* wgt_full = logits + NT * 8;                   // 2*NT f32 = 16 KB
  int* pexp_full = (int*)(wgt_full + 2 * NT);          // 2*NT int = 16 KB
  float* t2p = (float*)(pexp_full + 2 * NT);           // NPAIR*16 f32 = 64 KB
  // phase-B big (reuse xq/xk/xv region, 32 MB)
  bf16* cw1h = (bf16*)(base + ((size_t)48 << 20));     // NH*DFF bf16 = 8 MB
  bf16* cw3h = (bf16*)(base + ((size_t)56 << 20));     // 8 MB
  bf16* srp  = (bf16*)(base + ((size_t)64 << 20));     // NPAIR*DFF bf16 = 16 MB
  float* hsp = (float*)(base + ((size_t)48 << 20));    // NPAIR*2048 f32 = 8 MB, aliases cw1h (dead after sr_pack)
  bf16* sn = h_hi;

  detect_k<<<1, 64, 0, stream>>>(cosb, flag);

  // ---- attention block (fidelity via hi/lo split) ----
  rmsnorm_split<<<NT, blk, 0, stream>>>(flag, data, attn_w, h_hi, h_lo);
  zero_f<<<(NT * 16 * 4 + 255) / 256, blk, 0, stream>>>(tq, NT * 16 * 4);  // tq,tk,tv,to2
  gemm128_t<1><<<dim3(16,1,8), blk, 0, stream>>>(flag, h_hi, h_lo, 2048, qa, 0, 16, 16,
      tq, nullptr, 16, NT, 16, 2048, nullptr, 0, nullptr, 0, 0, 3);
  gemm128_t<1><<<dim3(16,1,8), blk, 0, stream>>>(flag, h_hi, h_lo, 2048, ka, 0, 16, 16,
      tk, nullptr, 16, NT, 16, 2048, nullptr, 0, nullptr, 0, 0, 3);
  gemm128_t<1><<<dim3(16,1,8), blk, 0, stream>>>(flag, h_hi, h_lo, 2048, va, 0, 16, 16,
      tv, nullptr, 16, NT, 16, 2048, nullptr, 0, nullptr, 0, 0, 3);
  gemm128_t<1><<<dim3(16,16,1), blk, 0, stream>>>(flag, h_hi, h_lo, 2048, wq, 0, 2048, 16,
      xq, nullptr, 2048, NT, 2048, 2048, tq, 16, qb, 0, 2048, 1);
  gemm128_t<1><<<dim3(16,8,1), blk, 0, stream>>>(flag, h_hi, h_lo, 2048, wk, 0, 1024, 16,
      xk, nullptr, 1024, NT, 1024, 2048, tk, 16, kb, 0, 1024, 1);
  gemm128_t<1><<<dim3(16,8,1), blk, 0, stream>>>(flag, h_hi, h_lo, 2048, wvw, 0, 1024, 16,
      xv, nullptr, 1024, NT, 1024, 2048, tv, 16, vb, 0, 1024, 1);
  rope_f32<<<8192, blk, 0, stream>>>(flag, xq, cosb, sinb, 16);
  rope_f32<<<4096, blk, 0, stream>>>(flag, xk, cosb, sinb, 8);
  flash_attn<<<2048, blk, 0, stream>>>(xq, xk, xv, h_hi, h_lo);   // o -> h_hi/h_lo
  zero_f<<<(NT * 16 + 255) / 256, blk, 0, stream>>>(to2, NT * 16);
  gemm128_t<1><<<dim3(16,1,8), blk, 0, stream>>>(flag, h_hi, h_lo, 2048, oa, 0, 16, 16,
      to2, nullptr, 16, NT, 16, 2048, nullptr, 0, nullptr, 0, 0, 3);
  gemm128_t<1><<<dim3(16,16,1), blk, 0, stream>>>(flag, h_hi, h_lo, 2048, wo, 0, 2048, 16,
      accb, nullptr, 2048, NT, 2048, 2048, to2, 16, ob, 0, 2048, 1);
  resid_k<<<(nElem + 255) / 256, blk, 0, stream>>>(flag, data, accb, data2, nElem);

  // ---- MoE prep ----
  rmsnorm_f32<<<NT, blk, 0, stream>>>(flag, data2, ffn_w, sn);
  logits_k<<<NT, blk, 0, stream>>>(flag, data2, ffn_w, gate_w, logits);
  route_pairs<<<8, blk, 0, stream>>>(logits, pexp_full, wgt_full);
  zero_f<<<(NT * 128 * 2 + 255) / 256, blk, 0, stream>>>(t1, NT * 128 * 2);   // t1,t3
  // all-expert LoRA t-projections (a1/a3 are [E][D][16]); split-K accumulate
  gemm128_t<0><<<dim3(16,1,8), blk, 0, stream>>>(flag, sn, nullptr, 2048, a1, 0, 16, 2048LL*16,
      t1, nullptr, 128, NT, 128, 2048, nullptr, 0, nullptr, 0, 0, 3);
  gemm128_t<0><<<dim3(16,1,8), blk, 0, stream>>>(flag, sn, nullptr, 2048, a3, 0, 16, 2048LL*16,
      t3, nullptr, 128, NT, 128, 2048, nullptr, 0, nullptr, 0, 0, 3);

  // ---- sparse MoE in 4 quarters of NH=512 rows, NPAIR pairs at fixed slots ----
  for (int hf = 0; hf < 4; hf++){
    int r0 = hf * NH;
    int P0 = r0 * 2;
    gemm128_t<0><<<dim3(4,64,1), blk, 0, stream>>>(flag, sn + (size_t)r0 * 2048, nullptr, 2048,
        w1, 0, 8192, 16, nullptr, cw1h, 8192, NH, 8192, 2048,
        nullptr, 0, nullptr, 0, 0, 0);
    gemm128_t<0><<<dim3(4,64,1), blk, 0, stream>>>(flag, sn + (size_t)r0 * 2048, nullptr, 2048,
        w3, 0, 8192, 16, nullptr, cw3h, 8192, NH, 8192, 2048,
        nullptr, 0, nullptr, 0, 0, 0);
    sr_pack<<<dim3(32, NPAIR), blk, 0, stream>>>(flag, cw1h, cw3h, t1, t3, b1, b3,
        r0, pexp_full + P0, srp);
    t2_pack<<<NPAIR, blk, 0, stream>>>(flag, srp, a2, pexp_full + P0, t2p);
    gemm_w2<<<dim3(8,16), blk, 0, stream>>>(flag, srp, w2, b2, t2p,
        pexp_full + P0, wgt_full + P0, hsp);
    gather_k<<<(NH * 2048 + 255) / 256, blk, 0, stream>>>(hsp, accb, r0);
  }
  final_k<<<(nElem + 255) / 256, blk, 0, stream>>>(flag, data2, accb, d_out, nElem);
}